// Round 1
// baseline (1901.804 us; speedup 1.0000x reference)
//
#include <hip/hip_runtime.h>

// ---------------- helpers ----------------

// Monotone encode: float -> uint32 such that float order == unsigned order.
// 0 is below every real encoding (only negative-NaN encodes < 0x00800000),
// so 0 doubles as the "-inf / no edge" sentinel after memset(0).
__device__ __forceinline__ unsigned fenc(float f) {
    unsigned u = __float_as_uint(f);
    return (u & 0x80000000u) ? ~u : (u | 0x80000000u);
}
__device__ __forceinline__ float fdec(unsigned u) {
    return __uint_as_float((u & 0x80000000u) ? (u & 0x7fffffffu) : ~u);
}

__device__ __forceinline__ float wredsum(float v) {
#pragma unroll
    for (int o = 32; o; o >>= 1) v += __shfl_xor(v, o);
    return v;
}

// ---------------- kernels ----------------

// rel = points - centers[labels]; x1 = relu([features, rel] @ feW + feb)
__global__ __launch_bounds__(256) void k_feat(
    const float* __restrict__ feat, const float* __restrict__ pts,
    const float* __restrict__ ctr, const int* __restrict__ lab,
    const float* __restrict__ W, const float* __restrict__ b,
    float* __restrict__ rel, float* __restrict__ x1, int n)
{
    int lane = threadIdx.x & 63;
    int wid  = blockIdx.x * (blockDim.x >> 6) + (threadIdx.x >> 6);
    int nw   = gridDim.x * (blockDim.x >> 6);
    for (int i = wid; i < n; i += nw) {
        int l = lab[i];
        float r0 = pts[i*3+0] - ctr[l*3+0];
        float r1 = pts[i*3+1] - ctr[l*3+1];
        float r2 = pts[i*3+2] - ctr[l*3+2];
        if (lane == 0) { rel[i*3+0] = r0; rel[i*3+1] = r1; rel[i*3+2] = r2; }
        float f0 = feat[i*4+0], f1 = feat[i*4+1], f2 = feat[i*4+2], f3 = feat[i*4+3];
        float acc = b[lane];
        acc = fmaf(f0, W[0*64+lane], acc);
        acc = fmaf(f1, W[1*64+lane], acc);
        acc = fmaf(f2, W[2*64+lane], acc);
        acc = fmaf(f3, W[3*64+lane], acc);
        acc = fmaf(r0, W[4*64+lane], acc);
        acc = fmaf(r1, W[5*64+lane], acc);
        acc = fmaf(r2, W[6*64+lane], acc);
        x1[(size_t)i*64+lane] = fmaxf(acc, 0.f);
    }
}

// Per-node precompute for a PointGNN layer:
//   delta = tanh(x@Wh + bh)
//   p = pos @ Wf[0:3] + x @ Wf[3:67]
//   q = (delta - pos) @ Wf[0:3] + bf
__global__ __launch_bounds__(256) void k_gnn_pre(
    const float* __restrict__ x, const float* __restrict__ pos,
    const float* __restrict__ Wh, const float* __restrict__ bh,
    const float* __restrict__ Wf, const float* __restrict__ bf,
    float* __restrict__ p, float* __restrict__ q, int n)
{
    __shared__ float Ws[67*64];
    for (int i = threadIdx.x; i < 67*64; i += blockDim.x) Ws[i] = Wf[i];
    __syncthreads();
    int lane = threadIdx.x & 63;
    int wid  = blockIdx.x * (blockDim.x >> 6) + (threadIdx.x >> 6);
    int nw   = gridDim.x * (blockDim.x >> 6);
    float bfl = bf[lane];
    float wh0 = Wh[lane*3+0], wh1 = Wh[lane*3+1], wh2 = Wh[lane*3+2];
    float bh0 = bh[0], bh1 = bh[1], bh2 = bh[2];
    float w0 = Ws[0*64+lane], w1 = Ws[1*64+lane], w2 = Ws[2*64+lane];
    for (int i = wid; i < n; i += nw) {
        float xv = x[(size_t)i*64+lane];
        float d0 = xv*wh0, d1 = xv*wh1, d2 = xv*wh2;
#pragma unroll
        for (int o = 32; o; o >>= 1) {
            d0 += __shfl_xor(d0, o); d1 += __shfl_xor(d1, o); d2 += __shfl_xor(d2, o);
        }
        d0 = tanhf(d0 + bh0); d1 = tanhf(d1 + bh1); d2 = tanhf(d2 + bh2);
        float p0 = pos[i*3+0], p1 = pos[i*3+1], p2 = pos[i*3+2];
        float accp = p0*w0 + p1*w1 + p2*w2;
        float accq = (d0-p0)*w0 + (d1-p1)*w1 + (d2-p2)*w2 + bfl;
        float acc = 0.f;
#pragma unroll 16
        for (int j = 0; j < 64; ++j) {
            float xj = __shfl(xv, j);
            acc = fmaf(xj, Ws[(3+j)*64+lane], acc);
        }
        p[(size_t)i*64+lane] = accp + acc;
        q[(size_t)i*64+lane] = accq;
    }
}

// Edge scatter-max: m[d,k] = max over edges (s,d) of p[s,k], via monotone-uint atomics.
// 16 threads per edge, float4 per thread. Pre-check is safe: m is monotone
// non-decreasing, so a stale (lower) cached read can only cause a redundant atomic.
__global__ __launch_bounds__(256) void k_edge_max(
    const int* __restrict__ edges, const float* __restrict__ p,
    unsigned* __restrict__ m, int E)
{
    int t = blockIdx.x * blockDim.x + threadIdx.x;
    int e = t >> 4;
    if (e >= E) return;
    int k4 = (t & 15) * 4;
    int s = edges[2*e+0];
    int d = edges[2*e+1];
    const float4 pv = *(const float4*)(p + (size_t)s*64 + k4);
    unsigned* addr = m + (size_t)d*64 + k4;
    uint4 cur = *(const uint4*)addr;
    unsigned ev;
    ev = fenc(pv.x); if (ev > cur.x) atomicMax(addr+0, ev);
    ev = fenc(pv.y); if (ev > cur.y) atomicMax(addr+1, ev);
    ev = fenc(pv.z); if (ev > cur.z) atomicMax(addr+2, ev);
    ev = fenc(pv.w); if (ev > cur.w) atomicMax(addr+3, ev);
}

// agg = (no edge) ? 0 : relu(mmax + q); out = relu(agg@Wg + bg) + xres
__global__ __launch_bounds__(256) void k_gnn_post(
    const unsigned* __restrict__ m, const float* __restrict__ q,
    const float* __restrict__ Wg, const float* __restrict__ bg,
    const float* __restrict__ xres, float* __restrict__ out, int n)
{
    __shared__ float Ws[64*64];
    for (int i = threadIdx.x; i < 64*64; i += blockDim.x) Ws[i] = Wg[i];
    __syncthreads();
    int lane = threadIdx.x & 63;
    int wid  = blockIdx.x * (blockDim.x >> 6) + (threadIdx.x >> 6);
    int nw   = gridDim.x * (blockDim.x >> 6);
    float bgl = bg[lane];
    for (int i = wid; i < n; i += nw) {
        unsigned u = m[(size_t)i*64+lane];
        float agg = (u == 0u) ? 0.f : fmaxf(fdec(u) + q[(size_t)i*64+lane], 0.f);
        float acc = 0.f;
#pragma unroll 16
        for (int j = 0; j < 64; ++j)
            acc = fmaf(__shfl(agg, j), Ws[j*64+lane], acc);
        out[(size_t)i*64+lane] = fmaxf(acc + bgl, 0.f) + xres[(size_t)i*64+lane];
    }
}

// h = relu([x2, rel] @ W + b); segment-max into cm[labels[i]] (monotone-uint atomics)
__global__ __launch_bounds__(256) void k_m2l_seg(
    const float* __restrict__ x2, const float* __restrict__ rel,
    const int* __restrict__ lab,
    const float* __restrict__ W, const float* __restrict__ b,
    unsigned* __restrict__ cm, int n)
{
    __shared__ float Ws[67*64];
    for (int i = threadIdx.x; i < 67*64; i += blockDim.x) Ws[i] = W[i];
    __syncthreads();
    int lane = threadIdx.x & 63;
    int wid  = blockIdx.x * (blockDim.x >> 6) + (threadIdx.x >> 6);
    int nw   = gridDim.x * (blockDim.x >> 6);
    float bl = b[lane];
    for (int i = wid; i < n; i += nw) {
        float xv = x2[(size_t)i*64+lane];
        float acc = 0.f;
#pragma unroll 16
        for (int j = 0; j < 64; ++j)
            acc = fmaf(__shfl(xv, j), Ws[j*64+lane], acc);
        float r0 = rel[i*3+0], r1 = rel[i*3+1], r2 = rel[i*3+2];
        acc += r0*Ws[64*64+lane] + r1*Ws[65*64+lane] + r2*Ws[66*64+lane] + bl;
        float h = fmaxf(acc, 0.f);
        unsigned ev = fenc(h);
        unsigned* addr = cm + (size_t)lab[i]*64 + lane;
        if (ev > *addr) atomicMax(addr, ev);
    }
}

__global__ __launch_bounds__(256) void k_dec(
    const unsigned* __restrict__ cm, float* __restrict__ c, int total)
{
    int t = blockIdx.x * blockDim.x + threadIdx.x;
    if (t < total) {
        unsigned u = cm[t];
        c[t] = (u == 0u) ? 0.f : fdec(u);
    }
}

// x5 = relu([c4[labels], rel] @ W + b)
__global__ __launch_bounds__(256) void k_l2m(
    const float* __restrict__ c4, const int* __restrict__ lab,
    const float* __restrict__ rel,
    const float* __restrict__ W, const float* __restrict__ b,
    float* __restrict__ x5, int n)
{
    __shared__ float Ws[67*64];
    for (int i = threadIdx.x; i < 67*64; i += blockDim.x) Ws[i] = W[i];
    __syncthreads();
    int lane = threadIdx.x & 63;
    int wid  = blockIdx.x * (blockDim.x >> 6) + (threadIdx.x >> 6);
    int nw   = gridDim.x * (blockDim.x >> 6);
    float bl = b[lane];
    for (int i = wid; i < n; i += nw) {
        int l = lab[i];
        float cv = c4[(size_t)l*64 + lane];
        float acc = 0.f;
#pragma unroll 16
        for (int j = 0; j < 64; ++j)
            acc = fmaf(__shfl(cv, j), Ws[j*64+lane], acc);
        float r0 = rel[i*3+0], r1 = rel[i*3+1], r2 = rel[i*3+2];
        acc += r0*Ws[64*64+lane] + r1*Ws[65*64+lane] + r2*Ws[66*64+lane] + bl;
        x5[(size_t)i*64+lane] = fmaxf(acc, 0.f);
    }
}

// Final GNN post + residual + classifier:
//   x6 = relu(agg@Wg+bg) + x5; fin = x6 + x2; t = relu(fin@W1+b1); out = t@W2+b2
__global__ __launch_bounds__(256) void k_gnn_post_final(
    const unsigned* __restrict__ m, const float* __restrict__ q,
    const float* __restrict__ Wg, const float* __restrict__ bg,
    const float* __restrict__ x5, const float* __restrict__ x2,
    const float* __restrict__ W1, const float* __restrict__ b1,
    const float* __restrict__ W2, const float* __restrict__ b2,
    float* __restrict__ out, int n)
{
    __shared__ float Wgs[64*64];
    __shared__ float W1s[64*64];
    __shared__ float W2s[64*4];
    for (int i = threadIdx.x; i < 64*64; i += blockDim.x) { Wgs[i] = Wg[i]; W1s[i] = W1[i]; }
    for (int i = threadIdx.x; i < 64*4; i += blockDim.x) W2s[i] = W2[i];
    __syncthreads();
    int lane = threadIdx.x & 63;
    int wid  = blockIdx.x * (blockDim.x >> 6) + (threadIdx.x >> 6);
    int nw   = gridDim.x * (blockDim.x >> 6);
    float bgl = bg[lane], b1l = b1[lane];
    for (int i = wid; i < n; i += nw) {
        unsigned u = m[(size_t)i*64+lane];
        float agg = (u == 0u) ? 0.f : fmaxf(fdec(u) + q[(size_t)i*64+lane], 0.f);
        float acc = 0.f;
#pragma unroll 16
        for (int j = 0; j < 64; ++j)
            acc = fmaf(__shfl(agg, j), Wgs[j*64+lane], acc);
        float fin = fmaxf(acc + bgl, 0.f) + x5[(size_t)i*64+lane] + x2[(size_t)i*64+lane];
        float acc1 = 0.f;
#pragma unroll 16
        for (int j = 0; j < 64; ++j)
            acc1 = fmaf(__shfl(fin, j), W1s[j*64+lane], acc1);
        float t = fmaxf(acc1 + b1l, 0.f);
        float o0 = wredsum(t * W2s[lane*4+0]);
        float o1 = wredsum(t * W2s[lane*4+1]);
        float o2 = wredsum(t * W2s[lane*4+2]);
        float o3 = wredsum(t * W2s[lane*4+3]);
        if (lane == 0) {
            out[(size_t)i*4+0] = o0 + b2[0];
            out[(size_t)i*4+1] = o1 + b2[1];
            out[(size_t)i*4+2] = o2 + b2[2];
            out[(size_t)i*4+3] = o3 + b2[3];
        }
    }
}

// ---------------- launch ----------------

extern "C" void kernel_launch(void* const* d_in, const int* in_sizes, int n_in,
                              void* d_out, int out_size, void* d_ws, size_t ws_size,
                              hipStream_t stream)
{
    const int N = 100000, M = 10000, E0 = 1600000, E1 = 320000;

    const float* feat = (const float*)d_in[0];
    const float* pts  = (const float*)d_in[1];
    const float* ctr  = (const float*)d_in[2];
    const int*   lab  = (const int*)d_in[3];
    const int*   e0   = (const int*)d_in[4];
    const int*   e1   = (const int*)d_in[5];
    const float* feW  = (const float*)d_in[6];
    const float* feb  = (const float*)d_in[7];
    const float* Wh   = (const float*)d_in[8];
    const float* bh   = (const float*)d_in[9];
    const float* Wf   = (const float*)d_in[10];
    const float* bf   = (const float*)d_in[11];
    const float* Wg   = (const float*)d_in[12];
    const float* bg   = (const float*)d_in[13];
    const float* m2lW = (const float*)d_in[14];
    const float* m2lb = (const float*)d_in[15];
    const float* l2mW = (const float*)d_in[16];
    const float* l2mb = (const float*)d_in[17];
    const float* cW1  = (const float*)d_in[18];
    const float* cb1  = (const float*)d_in[19];
    const float* cW2  = (const float*)d_in[20];
    const float* cb2  = (const float*)d_in[21];
    float* out = (float*)d_out;

    char* ws = (char*)d_ws;
    size_t off = 0;
    auto alloc = [&](size_t bytes) -> char* {
        char* r = ws + off; off += (bytes + 255) & ~(size_t)255; return r;
    };
    float*    rel = (float*)alloc((size_t)N*3*4);
    float*    x1  = (float*)alloc((size_t)N*64*4);   // reused as x5 later
    float*    x2  = (float*)alloc((size_t)N*64*4);
    float*    p   = (float*)alloc((size_t)N*64*4);
    float*    q   = (float*)alloc((size_t)N*64*4);
    unsigned* m   = (unsigned*)alloc((size_t)N*64*4); // also reused as cm
    float*    c   = (float*)alloc((size_t)M*64*4);
    float*    c4  = (float*)alloc((size_t)M*64*4);
    (void)ws_size; (void)in_sizes; (void)n_in; (void)out_size;

    dim3 blk(256);
    const int gridN = 2048;                       // wave-per-node grid-stride
    const int ge0 = (E0*16 + 255) / 256;
    const int ge1 = (E1*16 + 255) / 256;

    k_feat<<<gridN, blk, 0, stream>>>(feat, pts, ctr, lab, feW, feb, rel, x1, N);

    // ---- GNN layer 0 (points, l0_edges) ----
    hipMemsetAsync(m, 0, (size_t)N*64*4, stream);
    k_gnn_pre<<<gridN, blk, 0, stream>>>(x1, pts, Wh+0*64*3, bh+0*3, Wf+0*67*64, bf+0*64, p, q, N);
    k_edge_max<<<ge0, blk, 0, stream>>>(e0, p, m, E0);
    k_gnn_post<<<gridN, blk, 0, stream>>>(m, q, Wg+0*64*64, bg+0*64, x1, x2, N);

    // ---- m2l + segment-max over labels ----
    hipMemsetAsync(m, 0, (size_t)M*64*4, stream);  // reuse m as cluster max buf
    k_m2l_seg<<<gridN, blk, 0, stream>>>(x2, rel, lab, m2lW, m2lb, m, N);
    k_dec<<<(M*64 + 255)/256, blk, 0, stream>>>(m, c, M*64);

    // ---- GNN layer 1 (clusters, l1_edges) ----
    hipMemsetAsync(m, 0, (size_t)M*64*4, stream);
    k_gnn_pre<<<gridN, blk, 0, stream>>>(c, ctr, Wh+1*64*3, bh+1*3, Wf+1*67*64, bf+1*64, p, q, M);
    k_edge_max<<<ge1, blk, 0, stream>>>(e1, p, m, E1);
    k_gnn_post<<<gridN, blk, 0, stream>>>(m, q, Wg+1*64*64, bg+1*64, c, c4, M);

    // ---- l2m -> x5 (reuse x1 buffer) ----
    k_l2m<<<gridN, blk, 0, stream>>>(c4, lab, rel, l2mW, l2mb, x1, N);

    // ---- GNN layer 2 (points, l0_edges) + classifier ----
    hipMemsetAsync(m, 0, (size_t)N*64*4, stream);
    k_gnn_pre<<<gridN, blk, 0, stream>>>(x1, pts, Wh+2*64*3, bh+2*3, Wf+2*67*64, bf+2*64, p, q, N);
    k_edge_max<<<ge0, blk, 0, stream>>>(e0, p, m, E0);
    k_gnn_post_final<<<gridN, blk, 0, stream>>>(m, q, Wg+2*64*64, bg+2*64, x1, x2,
                                                cW1, cb1, cW2, cb2, out, N);
}

// Round 2
// 748.320 us; speedup vs baseline: 2.5414x; 2.5414x over previous
//
#include <hip/hip_runtime.h>

// ---------------- helpers ----------------

__device__ __forceinline__ float wredsum(float v) {
#pragma unroll
    for (int o = 32; o; o >>= 1) v += __shfl_xor(v, o);
    return v;
}

// ---------------- CSR build ----------------

__global__ __launch_bounds__(256) void k_hist_edges(
    const int2* __restrict__ e, int* __restrict__ deg, int E)
{
    int t = blockIdx.x * blockDim.x + threadIdx.x;
    if (t < E) atomicAdd(&deg[e[t].y], 1);
}

__global__ __launch_bounds__(256) void k_scatter_edges(
    const int2* __restrict__ e, int* __restrict__ cur, int* __restrict__ srcs, int E)
{
    int t = blockIdx.x * blockDim.x + threadIdx.x;
    if (t < E) {
        int2 ed = e[t];
        int pos = atomicAdd(&cur[ed.y], 1);
        srcs[pos] = ed.x;
    }
}

__global__ __launch_bounds__(256) void k_hist_lab(
    const int* __restrict__ lab, int* __restrict__ deg, int n)
{
    int t = blockIdx.x * blockDim.x + threadIdx.x;
    if (t < n) atomicAdd(&deg[lab[t]], 1);
}

__global__ __launch_bounds__(256) void k_scatter_lab(
    const int* __restrict__ lab, int* __restrict__ cur, int* __restrict__ srcs, int n)
{
    int t = blockIdx.x * blockDim.x + threadIdx.x;
    if (t < n) {
        int pos = atomicAdd(&cur[lab[t]], 1);
        srcs[pos] = t;
    }
}

// 3-kernel exclusive scan (chunk = 512, nb <= 512 assumed for the small pass)
__global__ __launch_bounds__(512) void k_scan_part(
    const int* __restrict__ deg, int* __restrict__ part, int n)
{
    __shared__ int red[512];
    int t = threadIdx.x;
    int idx = blockIdx.x * 512 + t;
    red[t] = (idx < n) ? deg[idx] : 0;
    __syncthreads();
    for (int o = 256; o; o >>= 1) { if (t < o) red[t] += red[t + o]; __syncthreads(); }
    if (t == 0) part[blockIdx.x] = red[0];
}

__global__ __launch_bounds__(512) void k_scan_small(int* __restrict__ part, int nb)
{
    __shared__ int a[512], b[512];
    int t = threadIdx.x;
    int v = (t < nb) ? part[t] : 0;
    a[t] = v; __syncthreads();
    int* src = a; int* dst = b;
    for (int o = 1; o < 512; o <<= 1) {
        dst[t] = src[t] + ((t >= o) ? src[t - o] : 0);
        __syncthreads();
        int* tmp = src; src = dst; dst = tmp;
    }
    if (t < nb) part[t] = src[t] - v;  // exclusive
}

__global__ __launch_bounds__(512) void k_scan_final(
    const int* __restrict__ deg, const int* __restrict__ part,
    int* __restrict__ rs, int* __restrict__ cur, int n, int total)
{
    __shared__ int a[512], b[512];
    int t = threadIdx.x;
    int idx = blockIdx.x * 512 + t;
    int v = (idx < n) ? deg[idx] : 0;
    a[t] = v; __syncthreads();
    int* src = a; int* dst = b;
    for (int o = 1; o < 512; o <<= 1) {
        dst[t] = src[t] + ((t >= o) ? src[t - o] : 0);
        __syncthreads();
        int* tmp = src; src = dst; dst = tmp;
    }
    int excl = src[t] - v + part[blockIdx.x];
    if (idx < n) { rs[idx] = excl; cur[idx] = excl; }
    if (idx == n - 1) rs[n] = total;
}

// ---------------- compute kernels ----------------

// rel = points - centers[labels]; x1 = relu([features, rel] @ feW + feb)
__global__ __launch_bounds__(256) void k_feat(
    const float* __restrict__ feat, const float* __restrict__ pts,
    const float* __restrict__ ctr, const int* __restrict__ lab,
    const float* __restrict__ W, const float* __restrict__ b,
    float* __restrict__ rel, float* __restrict__ x1, int n)
{
    int lane = threadIdx.x & 63;
    int wid  = blockIdx.x * (blockDim.x >> 6) + (threadIdx.x >> 6);
    int nw   = gridDim.x * (blockDim.x >> 6);
    float bl = b[lane];
    float w0 = W[0*64+lane], w1 = W[1*64+lane], w2 = W[2*64+lane], w3 = W[3*64+lane];
    float w4 = W[4*64+lane], w5 = W[5*64+lane], w6 = W[6*64+lane];
    for (int i = wid; i < n; i += nw) {
        int iu = __builtin_amdgcn_readfirstlane(i);
        int l = lab[iu];
        float r0 = pts[iu*3+0] - ctr[l*3+0];
        float r1 = pts[iu*3+1] - ctr[l*3+1];
        float r2 = pts[iu*3+2] - ctr[l*3+2];
        if (lane == 0) { rel[iu*3+0] = r0; rel[iu*3+1] = r1; rel[iu*3+2] = r2; }
        float f0 = feat[iu*4+0], f1 = feat[iu*4+1], f2 = feat[iu*4+2], f3 = feat[iu*4+3];
        float acc = bl;
        acc = fmaf(f0, w0, acc); acc = fmaf(f1, w1, acc);
        acc = fmaf(f2, w2, acc); acc = fmaf(f3, w3, acc);
        acc = fmaf(r0, w4, acc); acc = fmaf(r1, w5, acc); acc = fmaf(r2, w6, acc);
        x1[(size_t)iu*64+lane] = fmaxf(acc, 0.f);
    }
}

// Per-node precompute: delta = tanh(x@Wh+bh); p = pos@Wf[0:3] + x@Wf[3:67];
// q = (delta-pos)@Wf[0:3] + bf
__global__ __launch_bounds__(256) void k_gnn_pre(
    const float* __restrict__ x, const float* __restrict__ pos,
    const float* __restrict__ Wh, const float* __restrict__ bh,
    const float* __restrict__ Wf, const float* __restrict__ bf,
    float* __restrict__ p, float* __restrict__ q, int n)
{
    int lane = threadIdx.x & 63;
    int wid  = blockIdx.x * (blockDim.x >> 6) + (threadIdx.x >> 6);
    int nw   = gridDim.x * (blockDim.x >> 6);
    float wcol[64];
#pragma unroll
    for (int j = 0; j < 64; ++j) wcol[j] = Wf[(3+j)*64 + lane];
    float w0 = Wf[0*64+lane], w1 = Wf[1*64+lane], w2 = Wf[2*64+lane];
    float bfl = bf[lane];
    float wh0 = Wh[lane*3+0], wh1 = Wh[lane*3+1], wh2 = Wh[lane*3+2];
    float bh0 = bh[0], bh1 = bh[1], bh2 = bh[2];
    for (int i = wid; i < n; i += nw) {
        int iu = __builtin_amdgcn_readfirstlane(i);
        const float* xr = x + (size_t)iu*64;
        float xv = xr[lane];
        float d0 = xv*wh0, d1 = xv*wh1, d2 = xv*wh2;
#pragma unroll
        for (int o = 32; o; o >>= 1) {
            d0 += __shfl_xor(d0, o); d1 += __shfl_xor(d1, o); d2 += __shfl_xor(d2, o);
        }
        d0 = tanhf(d0 + bh0); d1 = tanhf(d1 + bh1); d2 = tanhf(d2 + bh2);
        float p0 = pos[iu*3+0], p1 = pos[iu*3+1], p2 = pos[iu*3+2];
        float acc = 0.f;
#pragma unroll
        for (int j = 0; j < 64; ++j) acc = fmaf(xr[j], wcol[j], acc);
        p[(size_t)iu*64+lane] = acc + p0*w0 + p1*w1 + p2*w2;
        q[(size_t)iu*64+lane] = (d0-p0)*w0 + (d1-p1)*w1 + (d2-p2)*w2 + bfl;
    }
}

// Per-destination gather-max over CSR, fused with relu(max+q) IN PLACE into q.
// Empty segment: acc=-1e30 -> relu(-1e30+q)=0, matching the reference's 0.
__global__ __launch_bounds__(256) void k_seg_max_gnn(
    const int* __restrict__ rs, const int* __restrict__ srcs,
    const float* __restrict__ p, float* __restrict__ q, int n)
{
    int lane = threadIdx.x & 63;
    int wid  = blockIdx.x * (blockDim.x >> 6) + (threadIdx.x >> 6);
    int nw   = gridDim.x * (blockDim.x >> 6);
    for (int d = wid; d < n; d += nw) {
        int du = __builtin_amdgcn_readfirstlane(d);
        int beg = rs[du], end = rs[du+1];
        float acc = -1e30f;
#pragma unroll 4
        for (int c = beg; c < end; ++c) {
            int s = srcs[c];
            acc = fmaxf(acc, p[(size_t)s*64 + lane]);
        }
        size_t o = (size_t)du*64 + lane;
        q[o] = fmaxf(acc + q[o], 0.f);
    }
}

// Plain segment-max (inputs are relu outputs >= 0): empty -> 0 via fmaxf(acc,0)
__global__ __launch_bounds__(256) void k_seg_max_plain(
    const int* __restrict__ rs, const int* __restrict__ srcs,
    const float* __restrict__ h, float* __restrict__ out, int n)
{
    int lane = threadIdx.x & 63;
    int wid  = blockIdx.x * (blockDim.x >> 6) + (threadIdx.x >> 6);
    int nw   = gridDim.x * (blockDim.x >> 6);
    for (int d = wid; d < n; d += nw) {
        int du = __builtin_amdgcn_readfirstlane(d);
        int beg = rs[du], end = rs[du+1];
        float acc = -1e30f;
#pragma unroll 4
        for (int c = beg; c < end; ++c) {
            int s = srcs[c];
            acc = fmaxf(acc, h[(size_t)s*64 + lane]);
        }
        out[(size_t)du*64+lane] = fmaxf(acc, 0.f);
    }
}

// out = relu(agg@Wg + bg) + xres   (agg rows wave-uniform -> scalar loads)
__global__ __launch_bounds__(256) void k_gnn_post(
    const float* __restrict__ agg, const float* __restrict__ Wg,
    const float* __restrict__ bg, const float* __restrict__ xres,
    float* __restrict__ out, int n)
{
    int lane = threadIdx.x & 63;
    int wid  = blockIdx.x * (blockDim.x >> 6) + (threadIdx.x >> 6);
    int nw   = gridDim.x * (blockDim.x >> 6);
    float wcol[64];
#pragma unroll
    for (int j = 0; j < 64; ++j) wcol[j] = Wg[j*64 + lane];
    float bgl = bg[lane];
    for (int i = wid; i < n; i += nw) {
        int iu = __builtin_amdgcn_readfirstlane(i);
        const float* ar = agg + (size_t)iu*64;
        float acc = 0.f;
#pragma unroll
        for (int j = 0; j < 64; ++j) acc = fmaf(ar[j], wcol[j], acc);
        size_t o = (size_t)iu*64 + lane;
        out[o] = fmaxf(acc + bgl, 0.f) + xres[o];
    }
}

// h = relu([x2, rel] @ W + b)  (row i of x2, rel[i])
__global__ __launch_bounds__(256) void k_m2l(
    const float* __restrict__ x2, const float* __restrict__ rel,
    const float* __restrict__ W, const float* __restrict__ b,
    float* __restrict__ h, int n)
{
    int lane = threadIdx.x & 63;
    int wid  = blockIdx.x * (blockDim.x >> 6) + (threadIdx.x >> 6);
    int nw   = gridDim.x * (blockDim.x >> 6);
    float wcol[64];
#pragma unroll
    for (int j = 0; j < 64; ++j) wcol[j] = W[j*64 + lane];
    float w64 = W[64*64+lane], w65 = W[65*64+lane], w66 = W[66*64+lane];
    float bl = b[lane];
    for (int i = wid; i < n; i += nw) {
        int iu = __builtin_amdgcn_readfirstlane(i);
        const float* xr = x2 + (size_t)iu*64;
        float acc = bl;
#pragma unroll
        for (int j = 0; j < 64; ++j) acc = fmaf(xr[j], wcol[j], acc);
        float r0 = rel[iu*3+0], r1 = rel[iu*3+1], r2 = rel[iu*3+2];
        acc += r0*w64 + r1*w65 + r2*w66;
        h[(size_t)iu*64+lane] = fmaxf(acc, 0.f);
    }
}

// x5 = relu([c4[labels], rel] @ W + b)
__global__ __launch_bounds__(256) void k_l2m(
    const float* __restrict__ c4, const int* __restrict__ lab,
    const float* __restrict__ rel,
    const float* __restrict__ W, const float* __restrict__ b,
    float* __restrict__ x5, int n)
{
    int lane = threadIdx.x & 63;
    int wid  = blockIdx.x * (blockDim.x >> 6) + (threadIdx.x >> 6);
    int nw   = gridDim.x * (blockDim.x >> 6);
    float wcol[64];
#pragma unroll
    for (int j = 0; j < 64; ++j) wcol[j] = W[j*64 + lane];
    float w64 = W[64*64+lane], w65 = W[65*64+lane], w66 = W[66*64+lane];
    float bl = b[lane];
    for (int i = wid; i < n; i += nw) {
        int iu = __builtin_amdgcn_readfirstlane(i);
        int l = lab[iu];
        const float* cr = c4 + (size_t)l*64;
        float acc = bl;
#pragma unroll
        for (int j = 0; j < 64; ++j) acc = fmaf(cr[j], wcol[j], acc);
        float r0 = rel[iu*3+0], r1 = rel[iu*3+1], r2 = rel[iu*3+2];
        acc += r0*w64 + r1*w65 + r2*w66;
        x5[(size_t)iu*64+lane] = fmaxf(acc, 0.f);
    }
}

// x6 = relu(agg@Wg+bg) + x5; fin = x6 + x2; t = relu(fin@W1+b1); out = t@W2+b2
__global__ __launch_bounds__(256) void k_gnn_post_final(
    const float* __restrict__ agg, const float* __restrict__ Wg,
    const float* __restrict__ bg,
    const float* __restrict__ x5, const float* __restrict__ x2,
    const float* __restrict__ W1, const float* __restrict__ b1,
    const float* __restrict__ W2, const float* __restrict__ b2,
    float* __restrict__ out, int n)
{
    int lane = threadIdx.x & 63;
    int wid  = blockIdx.x * (blockDim.x >> 6) + (threadIdx.x >> 6);
    int nw   = gridDim.x * (blockDim.x >> 6);
    float wg[64], w1c[64];
#pragma unroll
    for (int j = 0; j < 64; ++j) { wg[j] = Wg[j*64 + lane]; w1c[j] = W1[j*64 + lane]; }
    float w2c0 = W2[lane*4+0], w2c1 = W2[lane*4+1], w2c2 = W2[lane*4+2], w2c3 = W2[lane*4+3];
    float bgl = bg[lane], b1l = b1[lane];
    float b20 = b2[0], b21 = b2[1], b22 = b2[2], b23 = b2[3];
    for (int i = wid; i < n; i += nw) {
        int iu = __builtin_amdgcn_readfirstlane(i);
        const float* ar = agg + (size_t)iu*64;
        float acc = 0.f;
#pragma unroll
        for (int j = 0; j < 64; ++j) acc = fmaf(ar[j], wg[j], acc);
        size_t o = (size_t)iu*64 + lane;
        float fin = fmaxf(acc + bgl, 0.f) + x5[o] + x2[o];
        float acc1 = 0.f;
#pragma unroll
        for (int j = 0; j < 64; ++j) acc1 = fmaf(__shfl(fin, j), w1c[j], acc1);
        float t = fmaxf(acc1 + b1l, 0.f);
        float o0 = wredsum(t * w2c0);
        float o1 = wredsum(t * w2c1);
        float o2 = wredsum(t * w2c2);
        float o3 = wredsum(t * w2c3);
        if (lane == 0) {
            float4 ov = make_float4(o0 + b20, o1 + b21, o2 + b22, o3 + b23);
            *(float4*)(out + (size_t)iu*4) = ov;
        }
    }
}

// ---------------- launch ----------------

extern "C" void kernel_launch(void* const* d_in, const int* in_sizes, int n_in,
                              void* d_out, int out_size, void* d_ws, size_t ws_size,
                              hipStream_t stream)
{
    const int N = 100000, M = 10000, E0 = 1600000, E1 = 320000;

    const float* feat = (const float*)d_in[0];
    const float* pts  = (const float*)d_in[1];
    const float* ctr  = (const float*)d_in[2];
    const int*   lab  = (const int*)d_in[3];
    const int2*  e0   = (const int2*)d_in[4];
    const int2*  e1   = (const int2*)d_in[5];
    const float* feW  = (const float*)d_in[6];
    const float* feb  = (const float*)d_in[7];
    const float* Wh   = (const float*)d_in[8];
    const float* bh   = (const float*)d_in[9];
    const float* Wf   = (const float*)d_in[10];
    const float* bf   = (const float*)d_in[11];
    const float* Wg   = (const float*)d_in[12];
    const float* bg   = (const float*)d_in[13];
    const float* m2lW = (const float*)d_in[14];
    const float* m2lb = (const float*)d_in[15];
    const float* l2mW = (const float*)d_in[16];
    const float* l2mb = (const float*)d_in[17];
    const float* cW1  = (const float*)d_in[18];
    const float* cb1  = (const float*)d_in[19];
    const float* cW2  = (const float*)d_in[20];
    const float* cb2  = (const float*)d_in[21];
    float* out = (float*)d_out;

    char* ws = (char*)d_ws;
    size_t off = 0;
    auto alloc = [&](size_t bytes) -> char* {
        char* r = ws + off; off += (bytes + 255) & ~(size_t)255; return r;
    };
    float* rel  = (float*)alloc((size_t)N*3*4);
    float* x1   = (float*)alloc((size_t)N*64*4);   // reused as x5
    float* x2   = (float*)alloc((size_t)N*64*4);
    float* p    = (float*)alloc((size_t)N*64*4);   // p / h scratch
    float* q    = (float*)alloc((size_t)N*64*4);   // q, overwritten in place by agg
    float* c    = (float*)alloc((size_t)M*64*4);
    float* c4   = (float*)alloc((size_t)M*64*4);
    int* deg0   = (int*)alloc((size_t)N*4);
    int* rs0    = (int*)alloc((size_t)(N+1)*4);
    int* cur0   = (int*)alloc((size_t)N*4);
    int* srcs0  = (int*)alloc((size_t)E0*4);
    int* deg1   = (int*)alloc((size_t)M*4);
    int* rs1    = (int*)alloc((size_t)(M+1)*4);
    int* cur1   = (int*)alloc((size_t)M*4);
    int* srcs1  = (int*)alloc((size_t)E1*4);
    int* degL   = (int*)alloc((size_t)M*4);
    int* rsL    = (int*)alloc((size_t)(M+1)*4);
    int* curL   = (int*)alloc((size_t)M*4);
    int* srcsL  = (int*)alloc((size_t)N*4);
    int* part   = (int*)alloc((size_t)512*4);
    (void)ws_size; (void)in_sizes; (void)n_in; (void)out_size;

    dim3 blk(256);
    const int gridN = 2048;
    const int nb0 = (N + 511) / 512, nbM = (M + 511) / 512;

    // ---- build CSRs (l0 by dest, l1 by dest, points by label) ----
    hipMemsetAsync(deg0, 0, (size_t)N*4, stream);
    hipMemsetAsync(deg1, 0, (size_t)M*4, stream);
    hipMemsetAsync(degL, 0, (size_t)M*4, stream);
    k_hist_edges<<<(E0+255)/256, blk, 0, stream>>>(e0, deg0, E0);
    k_hist_edges<<<(E1+255)/256, blk, 0, stream>>>(e1, deg1, E1);
    k_hist_lab  <<<(N+255)/256, blk, 0, stream>>>(lab, degL, N);

    k_scan_part <<<nb0, 512, 0, stream>>>(deg0, part, N);
    k_scan_small<<<1, 512, 0, stream>>>(part, nb0);
    k_scan_final<<<nb0, 512, 0, stream>>>(deg0, part, rs0, cur0, N, E0);
    k_scatter_edges<<<(E0+255)/256, blk, 0, stream>>>(e0, cur0, srcs0, E0);

    k_scan_part <<<nbM, 512, 0, stream>>>(deg1, part, M);
    k_scan_small<<<1, 512, 0, stream>>>(part, nbM);
    k_scan_final<<<nbM, 512, 0, stream>>>(deg1, part, rs1, cur1, M, E1);
    k_scatter_edges<<<(E1+255)/256, blk, 0, stream>>>(e1, cur1, srcs1, E1);

    k_scan_part <<<nbM, 512, 0, stream>>>(degL, part, M);
    k_scan_small<<<1, 512, 0, stream>>>(part, nbM);
    k_scan_final<<<nbM, 512, 0, stream>>>(degL, part, rsL, curL, M, N);
    k_scatter_lab<<<(N+255)/256, blk, 0, stream>>>(lab, curL, srcsL, N);

    // ---- feature encoder ----
    k_feat<<<gridN, blk, 0, stream>>>(feat, pts, ctr, lab, feW, feb, rel, x1, N);

    // ---- GNN layer 0 (points, l0) ----
    k_gnn_pre<<<gridN, blk, 0, stream>>>(x1, pts, Wh+0*64*3, bh+0*3, Wf+0*67*64, bf+0*64, p, q, N);
    k_seg_max_gnn<<<gridN, blk, 0, stream>>>(rs0, srcs0, p, q, N);
    k_gnn_post<<<gridN, blk, 0, stream>>>(q, Wg+0*64*64, bg+0*64, x1, x2, N);

    // ---- m2l + label segment-max ----
    k_m2l<<<gridN, blk, 0, stream>>>(x2, rel, m2lW, m2lb, p, N);
    k_seg_max_plain<<<gridN, blk, 0, stream>>>(rsL, srcsL, p, c, M);

    // ---- GNN layer 1 (clusters, l1) ----
    k_gnn_pre<<<gridN, blk, 0, stream>>>(c, ctr, Wh+1*64*3, bh+1*3, Wf+1*67*64, bf+1*64, p, q, M);
    k_seg_max_gnn<<<gridN, blk, 0, stream>>>(rs1, srcs1, p, q, M);
    k_gnn_post<<<gridN, blk, 0, stream>>>(q, Wg+1*64*64, bg+1*64, c, c4, M);

    // ---- l2m (x5 into x1 buffer) ----
    k_l2m<<<gridN, blk, 0, stream>>>(c4, lab, rel, l2mW, l2mb, x1, N);

    // ---- GNN layer 2 (points, l0) + classifier ----
    k_gnn_pre<<<gridN, blk, 0, stream>>>(x1, pts, Wh+2*64*3, bh+2*3, Wf+2*67*64, bf+2*64, p, q, N);
    k_seg_max_gnn<<<gridN, blk, 0, stream>>>(rs0, srcs0, p, q, N);
    k_gnn_post_final<<<gridN, blk, 0, stream>>>(q, Wg+2*64*64, bg+2*64, x1, x2,
                                                cW1, cb1, cW2, cb2, out, N);
}

// Round 3
// 703.721 us; speedup vs baseline: 2.7025x; 1.0634x over previous
//
#include <hip/hip_runtime.h>

// ---------------- helpers ----------------

__device__ __forceinline__ float wredsum(float v) {
#pragma unroll
    for (int o = 32; o; o >>= 1) v += __shfl_xor(v, o);
    return v;
}

// ================= bucketed CSR build =================
// Bucket = dest >> 8 (256 dests per bucket).

// Global per-bucket histogram (LDS-staged).
__global__ __launch_bounds__(256) void k_bhist_e(
    const int2* __restrict__ e, int* __restrict__ gcnt, int E, int nb)
{
    __shared__ int c[400];
    for (int i = threadIdx.x; i < nb; i += 256) c[i] = 0;
    __syncthreads();
    for (int idx = blockIdx.x*256 + threadIdx.x; idx < E; idx += gridDim.x*256)
        atomicAdd(&c[e[idx].y >> 8], 1);
    __syncthreads();
    for (int i = threadIdx.x; i < nb; i += 256) if (c[i]) atomicAdd(&gcnt[i], c[i]);
}

__global__ __launch_bounds__(256) void k_bhist_l(
    const int* __restrict__ lab, int* __restrict__ gcnt, int n, int nb)
{
    __shared__ int c[400];
    for (int i = threadIdx.x; i < nb; i += 256) c[i] = 0;
    __syncthreads();
    for (int idx = blockIdx.x*256 + threadIdx.x; idx < n; idx += gridDim.x*256)
        atomicAdd(&c[lab[idx] >> 8], 1);
    __syncthreads();
    for (int i = threadIdx.x; i < nb; i += 256) if (c[i]) atomicAdd(&gcnt[i], c[i]);
}

// One block per CSR: exclusive-scan bucket counts -> base (nb+1 entries), cur.
__global__ __launch_bounds__(512) void k_bscan3(
    const int* c0, int* b0, int* u0, int nb0, int t0,
    const int* c1, int* b1, int* u1, int nb1, int t1,
    const int* c2, int* b2, int* u2, int nb2, int t2)
{
    const int* cnt; int* base; int* cur; int nb; int tot;
    if (blockIdx.x == 0) { cnt=c0; base=b0; cur=u0; nb=nb0; tot=t0; }
    else if (blockIdx.x == 1) { cnt=c1; base=b1; cur=u1; nb=nb1; tot=t1; }
    else { cnt=c2; base=b2; cur=u2; nb=nb2; tot=t2; }
    __shared__ int sc[512];
    int t = threadIdx.x;
    int v = (t < nb) ? cnt[t] : 0;
    sc[t] = v; __syncthreads();
    for (int o = 1; o < 512; o <<= 1) {
        int a = (t >= o) ? sc[t-o] : 0;
        __syncthreads();
        sc[t] += a;
        __syncthreads();
    }
    if (t < nb) { int ex = sc[t] - v; base[t] = ex; cur[t] = ex; }
    if (t == nb) base[nb] = tot;
}

// Phase A: LDS multisplit scatter into bucket-ordered ebuf (chunked writes).
#define BKT 512
#define EPT 8
__global__ __launch_bounds__(BKT) void k_bucket_e(
    const int2* __restrict__ e, int* __restrict__ cur,
    int2* __restrict__ ebuf, int E, int nb)
{
    __shared__ int cnt[400];
    __shared__ int chunk[400];
    int t = threadIdx.x;
    int base = blockIdx.x * (BKT*EPT);
    for (int i = t; i < nb; i += BKT) cnt[i] = 0;
    __syncthreads();
    int2 ed[EPT]; int rk[EPT];
#pragma unroll
    for (int k = 0; k < EPT; ++k) {
        int idx = base + k*BKT + t;
        if (idx < E) { ed[k] = e[idx]; rk[k] = atomicAdd(&cnt[ed[k].y >> 8], 1); }
        else rk[k] = -1;
    }
    __syncthreads();
    for (int i = t; i < nb; i += BKT) { int c = cnt[i]; if (c) chunk[i] = atomicAdd(&cur[i], c); }
    __syncthreads();
#pragma unroll
    for (int k = 0; k < EPT; ++k)
        if (rk[k] >= 0) ebuf[chunk[ed[k].y >> 8] + rk[k]] = ed[k];
}

__global__ __launch_bounds__(BKT) void k_bucket_l(
    const int* __restrict__ lab, int* __restrict__ cur,
    int2* __restrict__ ebuf, int n, int nb)
{
    __shared__ int cnt[400];
    __shared__ int chunk[400];
    int t = threadIdx.x;
    int base = blockIdx.x * (BKT*EPT);
    for (int i = t; i < nb; i += BKT) cnt[i] = 0;
    __syncthreads();
    int2 ed[EPT]; int rk[EPT];
#pragma unroll
    for (int k = 0; k < EPT; ++k) {
        int idx = base + k*BKT + t;
        if (idx < n) { ed[k] = make_int2(idx, lab[idx]); rk[k] = atomicAdd(&cnt[ed[k].y >> 8], 1); }
        else rk[k] = -1;
    }
    __syncthreads();
    for (int i = t; i < nb; i += BKT) { int c = cnt[i]; if (c) chunk[i] = atomicAdd(&cur[i], c); }
    __syncthreads();
#pragma unroll
    for (int k = 0; k < EPT; ++k)
        if (rk[k] >= 0) ebuf[chunk[ed[k].y >> 8] + rk[k]] = ed[k];
}

// Phase B: one block per bucket -> in-LDS per-dest hist+scan -> rs + srcs.
__global__ __launch_bounds__(512) void k_final(
    const int2* __restrict__ ebuf, const int* __restrict__ base_,
    int* __restrict__ rs, int* __restrict__ srcs, int ndst, int etot, int nb)
{
    __shared__ int h[256];
    __shared__ int sc[256];
    int b = blockIdx.x, t = threadIdx.x;
    int base = base_[b];
    int cnt  = base_[b+1] - base;
    int d0 = b << 8;
    if (t < 256) h[t] = 0;
    __syncthreads();
    for (int i = t; i < cnt; i += 512) atomicAdd(&h[ebuf[base+i].y - d0], 1);
    __syncthreads();
    int v = (t < 256) ? h[t] : 0;
    if (t < 256) sc[t] = v;
    __syncthreads();
    for (int o = 1; o < 256; o <<= 1) {
        int a = (t < 256 && t >= o) ? sc[t-o] : 0;
        __syncthreads();
        if (t < 256) sc[t] += a;
        __syncthreads();
    }
    if (t < 256) {
        int gpos = base + sc[t] - v;      // global start of dest d0+t
        if (d0 + t < ndst) rs[d0+t] = gpos;
        h[t] = gpos;                      // running cursor
    }
    if (b == nb-1 && t == 0) rs[ndst] = etot;
    __syncthreads();
    for (int i = t; i < cnt; i += 512) {
        int2 ed = ebuf[base+i];
        int pos = atomicAdd(&h[ed.y - d0], 1);
        srcs[pos] = ed.x;
    }
}

// ================= compute kernels =================

// rel, x1 = relu([feat, rel]@feW + feb); fused gnn_pre layer0 -> p, q
__global__ __launch_bounds__(256) void k_feat_pre0(
    const float* __restrict__ feat, const float* __restrict__ pts,
    const float* __restrict__ ctr, const int* __restrict__ lab,
    const float* __restrict__ Wfe, const float* __restrict__ bfe,
    const float* __restrict__ Wh, const float* __restrict__ bh,
    const float* __restrict__ Wf, const float* __restrict__ bf,
    float* __restrict__ rel, float* __restrict__ x1,
    float* __restrict__ p, float* __restrict__ q, int n)
{
    int lane = threadIdx.x & 63;
    int wid  = blockIdx.x * (blockDim.x >> 6) + (threadIdx.x >> 6);
    int nw   = gridDim.x * (blockDim.x >> 6);
    float fe0 = Wfe[0*64+lane], fe1 = Wfe[1*64+lane], fe2 = Wfe[2*64+lane], fe3 = Wfe[3*64+lane];
    float fe4 = Wfe[4*64+lane], fe5 = Wfe[5*64+lane], fe6 = Wfe[6*64+lane];
    float bfe_l = bfe[lane];
    float wcol[64];
#pragma unroll
    for (int j = 0; j < 64; ++j) wcol[j] = Wf[(3+j)*64 + lane];
    float w0 = Wf[0*64+lane], w1 = Wf[1*64+lane], w2 = Wf[2*64+lane];
    float bfl = bf[lane];
    float wh0 = Wh[lane*3+0], wh1 = Wh[lane*3+1], wh2 = Wh[lane*3+2];
    float bh0 = bh[0], bh1 = bh[1], bh2 = bh[2];
    for (int i = wid; i < n; i += nw) {
        int iu = __builtin_amdgcn_readfirstlane(i);
        int l = lab[iu];
        float p0 = pts[iu*3+0], p1 = pts[iu*3+1], p2 = pts[iu*3+2];
        float r0 = p0 - ctr[l*3+0], r1 = p1 - ctr[l*3+1], r2 = p2 - ctr[l*3+2];
        if (lane == 0) { rel[iu*3+0] = r0; rel[iu*3+1] = r1; rel[iu*3+2] = r2; }
        float f0 = feat[iu*4+0], f1 = feat[iu*4+1], f2 = feat[iu*4+2], f3 = feat[iu*4+3];
        float a = bfe_l;
        a = fmaf(f0, fe0, a); a = fmaf(f1, fe1, a); a = fmaf(f2, fe2, a); a = fmaf(f3, fe3, a);
        a = fmaf(r0, fe4, a); a = fmaf(r1, fe5, a); a = fmaf(r2, fe6, a);
        float xv = fmaxf(a, 0.f);
        x1[(size_t)iu*64+lane] = xv;
        float d0 = xv*wh0, d1 = xv*wh1, d2 = xv*wh2;
#pragma unroll
        for (int o = 32; o; o >>= 1) {
            d0 += __shfl_xor(d0, o); d1 += __shfl_xor(d1, o); d2 += __shfl_xor(d2, o);
        }
        d0 = tanhf(d0 + bh0); d1 = tanhf(d1 + bh1); d2 = tanhf(d2 + bh2);
        float acc = 0.f;
#pragma unroll
        for (int j = 0; j < 64; ++j) acc = fmaf(__shfl(xv, j), wcol[j], acc);
        p[(size_t)iu*64+lane] = acc + p0*w0 + p1*w1 + p2*w2;
        q[(size_t)iu*64+lane] = (d0-p0)*w0 + (d1-p1)*w1 + (d2-p2)*w2 + bfl;
    }
}

// CSR gather-max fused with relu(max+q) in place into q. Empty -> 0 via -1e30.
__global__ __launch_bounds__(256) void k_seg_max_gnn(
    const int* __restrict__ rs, const int* __restrict__ srcs,
    const float* __restrict__ p, float* __restrict__ q, int n)
{
    int lane = threadIdx.x & 63;
    int wid  = blockIdx.x * (blockDim.x >> 6) + (threadIdx.x >> 6);
    int nw   = gridDim.x * (blockDim.x >> 6);
    for (int d = wid; d < n; d += nw) {
        int du = __builtin_amdgcn_readfirstlane(d);
        int beg = rs[du], end = rs[du+1];
        float acc = -1e30f;
#pragma unroll 4
        for (int c = beg; c < end; ++c) {
            int s = srcs[c];
            acc = fmaxf(acc, p[(size_t)s*64 + lane]);
        }
        size_t o = (size_t)du*64 + lane;
        q[o] = fmaxf(acc + q[o], 0.f);
    }
}

// x2 = relu(agg@Wg+bg)+x1; h = relu([x2,rel]@Wm+bm)   (fused post0 + m2l)
__global__ __launch_bounds__(256) void k_post_m2l(
    const float* __restrict__ agg, const float* __restrict__ Wg,
    const float* __restrict__ bg, const float* __restrict__ x1,
    const float* __restrict__ rel,
    const float* __restrict__ Wm, const float* __restrict__ bm,
    float* __restrict__ x2, float* __restrict__ h, int n)
{
    int lane = threadIdx.x & 63;
    int wid  = blockIdx.x * (blockDim.x >> 6) + (threadIdx.x >> 6);
    int nw   = gridDim.x * (blockDim.x >> 6);
    float wg[64], wm[64];
#pragma unroll
    for (int j = 0; j < 64; ++j) { wg[j] = Wg[j*64 + lane]; wm[j] = Wm[j*64 + lane]; }
    float wm64 = Wm[64*64+lane], wm65 = Wm[65*64+lane], wm66 = Wm[66*64+lane];
    float bgl = bg[lane], bml = bm[lane];
    for (int i = wid; i < n; i += nw) {
        int iu = __builtin_amdgcn_readfirstlane(i);
        const float* ar = agg + (size_t)iu*64;
        float acc = 0.f;
#pragma unroll
        for (int j = 0; j < 64; ++j) acc = fmaf(ar[j], wg[j], acc);
        size_t o = (size_t)iu*64 + lane;
        float x2v = fmaxf(acc + bgl, 0.f) + x1[o];
        x2[o] = x2v;
        float a2 = bml;
#pragma unroll
        for (int j = 0; j < 64; ++j) a2 = fmaf(__shfl(x2v, j), wm[j], a2);
        float r0 = rel[iu*3+0], r1 = rel[iu*3+1], r2 = rel[iu*3+2];
        a2 += r0*wm64 + r1*wm65 + r2*wm66;
        h[o] = fmaxf(a2, 0.f);
    }
}

// c = segmax(h by labels); fused gnn_pre layer1 -> pa, qa   (M nodes)
__global__ __launch_bounds__(256) void k_seglab_pre1(
    const int* __restrict__ rsL, const int* __restrict__ srcsL,
    const float* __restrict__ h, const float* __restrict__ pos,
    const float* __restrict__ Wh, const float* __restrict__ bh,
    const float* __restrict__ Wf, const float* __restrict__ bf,
    float* __restrict__ c, float* __restrict__ pa, float* __restrict__ qa, int m)
{
    int lane = threadIdx.x & 63;
    int wid  = blockIdx.x * (blockDim.x >> 6) + (threadIdx.x >> 6);
    int nw   = gridDim.x * (blockDim.x >> 6);
    float wcol[64];
#pragma unroll
    for (int j = 0; j < 64; ++j) wcol[j] = Wf[(3+j)*64 + lane];
    float w0 = Wf[0*64+lane], w1 = Wf[1*64+lane], w2 = Wf[2*64+lane];
    float bfl = bf[lane];
    float wh0 = Wh[lane*3+0], wh1 = Wh[lane*3+1], wh2 = Wh[lane*3+2];
    float bh0 = bh[0], bh1 = bh[1], bh2 = bh[2];
    for (int d = wid; d < m; d += nw) {
        int du = __builtin_amdgcn_readfirstlane(d);
        int beg = rsL[du], end = rsL[du+1];
        float acc = -1e30f;
#pragma unroll 4
        for (int cc = beg; cc < end; ++cc) {
            int s = srcsL[cc];
            acc = fmaxf(acc, h[(size_t)s*64 + lane]);
        }
        float cv = fmaxf(acc, 0.f);
        c[(size_t)du*64+lane] = cv;
        float d0 = cv*wh0, d1 = cv*wh1, d2 = cv*wh2;
#pragma unroll
        for (int o = 32; o; o >>= 1) {
            d0 += __shfl_xor(d0, o); d1 += __shfl_xor(d1, o); d2 += __shfl_xor(d2, o);
        }
        d0 = tanhf(d0 + bh0); d1 = tanhf(d1 + bh1); d2 = tanhf(d2 + bh2);
        float p0 = pos[du*3+0], p1 = pos[du*3+1], p2 = pos[du*3+2];
        float am = 0.f;
#pragma unroll
        for (int j = 0; j < 64; ++j) am = fmaf(__shfl(cv, j), wcol[j], am);
        pa[(size_t)du*64+lane] = am + p0*w0 + p1*w1 + p2*w2;
        qa[(size_t)du*64+lane] = (d0-p0)*w0 + (d1-p1)*w1 + (d2-p2)*w2 + bfl;
    }
}

// out = relu(agg@Wg + bg) + xres
__global__ __launch_bounds__(256) void k_gnn_post(
    const float* __restrict__ agg, const float* __restrict__ Wg,
    const float* __restrict__ bg, const float* __restrict__ xres,
    float* __restrict__ out, int n)
{
    int lane = threadIdx.x & 63;
    int wid  = blockIdx.x * (blockDim.x >> 6) + (threadIdx.x >> 6);
    int nw   = gridDim.x * (blockDim.x >> 6);
    float wcol[64];
#pragma unroll
    for (int j = 0; j < 64; ++j) wcol[j] = Wg[j*64 + lane];
    float bgl = bg[lane];
    for (int i = wid; i < n; i += nw) {
        int iu = __builtin_amdgcn_readfirstlane(i);
        const float* ar = agg + (size_t)iu*64;
        float acc = 0.f;
#pragma unroll
        for (int j = 0; j < 64; ++j) acc = fmaf(ar[j], wcol[j], acc);
        size_t o = (size_t)iu*64 + lane;
        out[o] = fmaxf(acc + bgl, 0.f) + xres[o];
    }
}

// x5 = relu([c4[lab], rel]@Wm+bm); fused gnn_pre layer2 -> p, q
__global__ __launch_bounds__(256) void k_l2m_pre2(
    const float* __restrict__ c4, const int* __restrict__ lab,
    const float* __restrict__ rel, const float* __restrict__ pts,
    const float* __restrict__ Wm, const float* __restrict__ bm,
    const float* __restrict__ Wh, const float* __restrict__ bh,
    const float* __restrict__ Wf, const float* __restrict__ bf,
    float* __restrict__ x5, float* __restrict__ p, float* __restrict__ q, int n)
{
    int lane = threadIdx.x & 63;
    int wid  = blockIdx.x * (blockDim.x >> 6) + (threadIdx.x >> 6);
    int nw   = gridDim.x * (blockDim.x >> 6);
    float wm[64], wf[64];
#pragma unroll
    for (int j = 0; j < 64; ++j) { wm[j] = Wm[j*64 + lane]; wf[j] = Wf[(3+j)*64 + lane]; }
    float wm64 = Wm[64*64+lane], wm65 = Wm[65*64+lane], wm66 = Wm[66*64+lane];
    float w0 = Wf[0*64+lane], w1 = Wf[1*64+lane], w2 = Wf[2*64+lane];
    float bml = bm[lane], bfl = bf[lane];
    float wh0 = Wh[lane*3+0], wh1 = Wh[lane*3+1], wh2 = Wh[lane*3+2];
    float bh0 = bh[0], bh1 = bh[1], bh2 = bh[2];
    for (int i = wid; i < n; i += nw) {
        int iu = __builtin_amdgcn_readfirstlane(i);
        int l = lab[iu];
        const float* cr = c4 + (size_t)l*64;
        float acc = bml;
#pragma unroll
        for (int j = 0; j < 64; ++j) acc = fmaf(cr[j], wm[j], acc);
        float r0 = rel[iu*3+0], r1 = rel[iu*3+1], r2 = rel[iu*3+2];
        acc += r0*wm64 + r1*wm65 + r2*wm66;
        float xv = fmaxf(acc, 0.f);
        size_t o = (size_t)iu*64 + lane;
        x5[o] = xv;
        float d0 = xv*wh0, d1 = xv*wh1, d2 = xv*wh2;
#pragma unroll
        for (int oo = 32; oo; oo >>= 1) {
            d0 += __shfl_xor(d0, oo); d1 += __shfl_xor(d1, oo); d2 += __shfl_xor(d2, oo);
        }
        d0 = tanhf(d0 + bh0); d1 = tanhf(d1 + bh1); d2 = tanhf(d2 + bh2);
        float p0 = pts[iu*3+0], p1 = pts[iu*3+1], p2 = pts[iu*3+2];
        float am = 0.f;
#pragma unroll
        for (int j = 0; j < 64; ++j) am = fmaf(__shfl(xv, j), wf[j], am);
        p[o] = am + p0*w0 + p1*w1 + p2*w2;
        q[o] = (d0-p0)*w0 + (d1-p1)*w1 + (d2-p2)*w2 + bfl;
    }
}

// x6 = relu(agg@Wg+bg)+x5; fin = x6+x2; t = relu(fin@W1+b1); out = t@W2+b2
__global__ __launch_bounds__(256) void k_gnn_post_final(
    const float* __restrict__ agg, const float* __restrict__ Wg,
    const float* __restrict__ bg,
    const float* __restrict__ x5, const float* __restrict__ x2,
    const float* __restrict__ W1, const float* __restrict__ b1,
    const float* __restrict__ W2, const float* __restrict__ b2,
    float* __restrict__ out, int n)
{
    int lane = threadIdx.x & 63;
    int wid  = blockIdx.x * (blockDim.x >> 6) + (threadIdx.x >> 6);
    int nw   = gridDim.x * (blockDim.x >> 6);
    float wg[64], w1c[64];
#pragma unroll
    for (int j = 0; j < 64; ++j) { wg[j] = Wg[j*64 + lane]; w1c[j] = W1[j*64 + lane]; }
    float w2c0 = W2[lane*4+0], w2c1 = W2[lane*4+1], w2c2 = W2[lane*4+2], w2c3 = W2[lane*4+3];
    float bgl = bg[lane], b1l = b1[lane];
    float b20 = b2[0], b21 = b2[1], b22 = b2[2], b23 = b2[3];
    for (int i = wid; i < n; i += nw) {
        int iu = __builtin_amdgcn_readfirstlane(i);
        const float* ar = agg + (size_t)iu*64;
        float acc = 0.f;
#pragma unroll
        for (int j = 0; j < 64; ++j) acc = fmaf(ar[j], wg[j], acc);
        size_t o = (size_t)iu*64 + lane;
        float fin = fmaxf(acc + bgl, 0.f) + x5[o] + x2[o];
        float acc1 = 0.f;
#pragma unroll
        for (int j = 0; j < 64; ++j) acc1 = fmaf(__shfl(fin, j), w1c[j], acc1);
        float t = fmaxf(acc1 + b1l, 0.f);
        float o0 = wredsum(t * w2c0);
        float o1 = wredsum(t * w2c1);
        float o2 = wredsum(t * w2c2);
        float o3 = wredsum(t * w2c3);
        if (lane == 0) {
            float4 ov = make_float4(o0 + b20, o1 + b21, o2 + b22, o3 + b23);
            *(float4*)(out + (size_t)iu*4) = ov;
        }
    }
}

// ---------------- launch ----------------

extern "C" void kernel_launch(void* const* d_in, const int* in_sizes, int n_in,
                              void* d_out, int out_size, void* d_ws, size_t ws_size,
                              hipStream_t stream)
{
    const int N = 100000, M = 10000, E0 = 1600000, E1 = 320000;
    const int NB0 = (N + 255) / 256;   // 391
    const int NB1 = (M + 255) / 256;   // 40
    const int NBL = (M + 255) / 256;   // 40

    const float* feat = (const float*)d_in[0];
    const float* pts  = (const float*)d_in[1];
    const float* ctr  = (const float*)d_in[2];
    const int*   lab  = (const int*)d_in[3];
    const int2*  e0   = (const int2*)d_in[4];
    const int2*  e1   = (const int2*)d_in[5];
    const float* feW  = (const float*)d_in[6];
    const float* feb  = (const float*)d_in[7];
    const float* Wh   = (const float*)d_in[8];
    const float* bh   = (const float*)d_in[9];
    const float* Wf   = (const float*)d_in[10];
    const float* bf   = (const float*)d_in[11];
    const float* Wg   = (const float*)d_in[12];
    const float* bg   = (const float*)d_in[13];
    const float* m2lW = (const float*)d_in[14];
    const float* m2lb = (const float*)d_in[15];
    const float* l2mW = (const float*)d_in[16];
    const float* l2mb = (const float*)d_in[17];
    const float* cW1  = (const float*)d_in[18];
    const float* cb1  = (const float*)d_in[19];
    const float* cW2  = (const float*)d_in[20];
    const float* cb2  = (const float*)d_in[21];
    float* out = (float*)d_out;

    char* ws = (char*)d_ws;
    size_t off = 0;
    auto alloc = [&](size_t bytes) -> char* {
        char* r = ws + off; off += (bytes + 255) & ~(size_t)255; return r;
    };
    float* rel   = (float*)alloc((size_t)N*3*4);
    float* x1    = (float*)alloc((size_t)N*64*4);   // x1, later x5
    float* x2    = (float*)alloc((size_t)N*64*4);   // also hosts ebufs pre-compute
    float* p     = (float*)alloc((size_t)N*64*4);   // p0 / h / p2
    float* q     = (float*)alloc((size_t)N*64*4);   // q0/agg, [p1|q1], q2
    float* c     = (float*)alloc((size_t)M*64*4);
    float* c4    = (float*)alloc((size_t)M*64*4);
    int* rs0     = (int*)alloc((size_t)(N+1)*4);
    int* srcs0   = (int*)alloc((size_t)E0*4);
    int* rs1     = (int*)alloc((size_t)(M+1)*4);
    int* srcs1   = (int*)alloc((size_t)E1*4);
    int* rsL     = (int*)alloc((size_t)(M+1)*4);
    int* srcsL   = (int*)alloc((size_t)N*4);
    int* cnt0    = (int*)alloc((size_t)NB0*4);
    int* cnt1    = (int*)alloc((size_t)NB1*4);
    int* cntL    = (int*)alloc((size_t)NBL*4);
    int* base0   = (int*)alloc((size_t)(NB0+1)*4);
    int* base1   = (int*)alloc((size_t)(NB1+1)*4);
    int* baseL   = (int*)alloc((size_t)(NBL+1)*4);
    int* cur0    = (int*)alloc((size_t)NB0*4);
    int* cur1    = (int*)alloc((size_t)NB1*4);
    int* curL    = (int*)alloc((size_t)NBL*4);
    (void)ws_size; (void)in_sizes; (void)n_in; (void)out_size;

    // ebufs aliased into x2 region (dead until compute phase): 12.8+2.56+0.8 MB <= 25.6 MB
    int2* ebuf0 = (int2*)x2;
    int2* ebuf1 = ebuf0 + E0;
    int2* ebufL = ebuf1 + E1;

    dim3 blk(256);
    const int gridN = 2048, gridM = 640;

    // ---- CSR builds ----
    hipMemsetAsync(cnt0, 0, (size_t)NB0*4, stream);
    hipMemsetAsync(cnt1, 0, (size_t)NB1*4, stream);
    hipMemsetAsync(cntL, 0, (size_t)NBL*4, stream);
    k_bhist_e<<<1024, blk, 0, stream>>>(e0, cnt0, E0, NB0);
    k_bhist_e<<<512,  blk, 0, stream>>>(e1, cnt1, E1, NB1);
    k_bhist_l<<<512,  blk, 0, stream>>>(lab, cntL, N, NBL);
    k_bscan3<<<3, 512, 0, stream>>>(cnt0, base0, cur0, NB0, E0,
                                    cnt1, base1, cur1, NB1, E1,
                                    cntL, baseL, curL, NBL, N);
    k_bucket_e<<<(E0 + BKT*EPT - 1)/(BKT*EPT), BKT, 0, stream>>>(e0, cur0, ebuf0, E0, NB0);
    k_bucket_e<<<(E1 + BKT*EPT - 1)/(BKT*EPT), BKT, 0, stream>>>(e1, cur1, ebuf1, E1, NB1);
    k_bucket_l<<<(N  + BKT*EPT - 1)/(BKT*EPT), BKT, 0, stream>>>(lab, curL, ebufL, N, NBL);
    k_final<<<NB0, 512, 0, stream>>>(ebuf0, base0, rs0, srcs0, N, E0, NB0);
    k_final<<<NB1, 512, 0, stream>>>(ebuf1, base1, rs1, srcs1, M, E1, NB1);
    k_final<<<NBL, 512, 0, stream>>>(ebufL, baseL, rsL, srcsL, M, N, NBL);

    // ---- layer 0 ----
    k_feat_pre0<<<gridN, blk, 0, stream>>>(feat, pts, ctr, lab, feW, feb,
                                           Wh+0*64*3, bh+0*3, Wf+0*67*64, bf+0*64,
                                           rel, x1, p, q, N);
    k_seg_max_gnn<<<gridN, blk, 0, stream>>>(rs0, srcs0, p, q, N);
    k_post_m2l<<<gridN, blk, 0, stream>>>(q, Wg+0*64*64, bg+0*64, x1, rel,
                                          m2lW, m2lb, x2, p, N);

    // ---- layer 1 (clusters) ----
    float* p1 = q;                 // M*64
    float* q1 = q + (size_t)M*64;  // M*64
    k_seglab_pre1<<<gridM, blk, 0, stream>>>(rsL, srcsL, p, ctr,
                                             Wh+1*64*3, bh+1*3, Wf+1*67*64, bf+1*64,
                                             c, p1, q1, M);
    k_seg_max_gnn<<<gridM, blk, 0, stream>>>(rs1, srcs1, p1, q1, M);
    k_gnn_post<<<gridM, blk, 0, stream>>>(q1, Wg+1*64*64, bg+1*64, c, c4, M);

    // ---- l2m + layer 2 + classifier ----
    k_l2m_pre2<<<gridN, blk, 0, stream>>>(c4, lab, rel, pts, l2mW, l2mb,
                                          Wh+2*64*3, bh+2*3, Wf+2*67*64, bf+2*64,
                                          x1, p, q, N);
    k_seg_max_gnn<<<gridN, blk, 0, stream>>>(rs0, srcs0, p, q, N);
    k_gnn_post_final<<<gridN, blk, 0, stream>>>(q, Wg+2*64*64, bg+2*64, x1, x2,
                                                cW1, cb1, cW2, cb2, out, N);
}

// Round 4
// 542.327 us; speedup vs baseline: 3.5068x; 1.2976x over previous
//
#include <hip/hip_runtime.h>

// ---------------- helpers ----------------

__device__ __forceinline__ float wredsum(float v) {
#pragma unroll
    for (int o = 32; o; o >>= 1) v += __shfl_xor(v, o);
    return v;
}

// lane-broadcast via v_readlane (const lane in unrolled loops) -> SGPR operand fma
__device__ __forceinline__ float bcast(float v, int l) {
    return __int_as_float(__builtin_amdgcn_readlane(__float_as_int(v), l));
}

// ================= bucketed CSR build =================
// Bucket = dest >> 8 (256 dests per bucket).

__global__ __launch_bounds__(256) void k_bhist_e(
    const int2* __restrict__ e, int* __restrict__ gcnt, int E, int nb)
{
    __shared__ int c[400];
    for (int i = threadIdx.x; i < nb; i += 256) c[i] = 0;
    __syncthreads();
    for (int idx = blockIdx.x*256 + threadIdx.x; idx < E; idx += gridDim.x*256)
        atomicAdd(&c[e[idx].y >> 8], 1);
    __syncthreads();
    for (int i = threadIdx.x; i < nb; i += 256) if (c[i]) atomicAdd(&gcnt[i], c[i]);
}

__global__ __launch_bounds__(256) void k_bhist_l(
    const int* __restrict__ lab, int* __restrict__ gcnt, int n, int nb)
{
    __shared__ int c[400];
    for (int i = threadIdx.x; i < nb; i += 256) c[i] = 0;
    __syncthreads();
    for (int idx = blockIdx.x*256 + threadIdx.x; idx < n; idx += gridDim.x*256)
        atomicAdd(&c[lab[idx] >> 8], 1);
    __syncthreads();
    for (int i = threadIdx.x; i < nb; i += 256) if (c[i]) atomicAdd(&gcnt[i], c[i]);
}

__global__ __launch_bounds__(512) void k_bscan3(
    const int* c0, int* b0, int* u0, int nb0, int t0,
    const int* c1, int* b1, int* u1, int nb1, int t1,
    const int* c2, int* b2, int* u2, int nb2, int t2)
{
    const int* cnt; int* base; int* cur; int nb; int tot;
    if (blockIdx.x == 0) { cnt=c0; base=b0; cur=u0; nb=nb0; tot=t0; }
    else if (blockIdx.x == 1) { cnt=c1; base=b1; cur=u1; nb=nb1; tot=t1; }
    else { cnt=c2; base=b2; cur=u2; nb=nb2; tot=t2; }
    __shared__ int sc[512];
    int t = threadIdx.x;
    int v = (t < nb) ? cnt[t] : 0;
    sc[t] = v; __syncthreads();
    for (int o = 1; o < 512; o <<= 1) {
        int a = (t >= o) ? sc[t-o] : 0;
        __syncthreads();
        sc[t] += a;
        __syncthreads();
    }
    if (t < nb) { int ex = sc[t] - v; base[t] = ex; cur[t] = ex; }
    if (t == nb) base[nb] = tot;
}

#define BKT 512
#define EPT 8
__global__ __launch_bounds__(BKT) void k_bucket_e(
    const int2* __restrict__ e, int* __restrict__ cur,
    int2* __restrict__ ebuf, int E, int nb)
{
    __shared__ int cnt[400];
    __shared__ int chunk[400];
    int t = threadIdx.x;
    int base = blockIdx.x * (BKT*EPT);
    for (int i = t; i < nb; i += BKT) cnt[i] = 0;
    __syncthreads();
    int2 ed[EPT]; int rk[EPT];
#pragma unroll
    for (int k = 0; k < EPT; ++k) {
        int idx = base + k*BKT + t;
        if (idx < E) { ed[k] = e[idx]; rk[k] = atomicAdd(&cnt[ed[k].y >> 8], 1); }
        else rk[k] = -1;
    }
    __syncthreads();
    for (int i = t; i < nb; i += BKT) { int c = cnt[i]; if (c) chunk[i] = atomicAdd(&cur[i], c); }
    __syncthreads();
#pragma unroll
    for (int k = 0; k < EPT; ++k)
        if (rk[k] >= 0) ebuf[chunk[ed[k].y >> 8] + rk[k]] = ed[k];
}

__global__ __launch_bounds__(BKT) void k_bucket_l(
    const int* __restrict__ lab, int* __restrict__ cur,
    int2* __restrict__ ebuf, int n, int nb)
{
    __shared__ int cnt[400];
    __shared__ int chunk[400];
    int t = threadIdx.x;
    int base = blockIdx.x * (BKT*EPT);
    for (int i = t; i < nb; i += BKT) cnt[i] = 0;
    __syncthreads();
    int2 ed[EPT]; int rk[EPT];
#pragma unroll
    for (int k = 0; k < EPT; ++k) {
        int idx = base + k*BKT + t;
        if (idx < n) { ed[k] = make_int2(idx, lab[idx]); rk[k] = atomicAdd(&cnt[ed[k].y >> 8], 1); }
        else rk[k] = -1;
    }
    __syncthreads();
    for (int i = t; i < nb; i += BKT) { int c = cnt[i]; if (c) chunk[i] = atomicAdd(&cur[i], c); }
    __syncthreads();
#pragma unroll
    for (int k = 0; k < EPT; ++k)
        if (rk[k] >= 0) ebuf[chunk[ed[k].y >> 8] + rk[k]] = ed[k];
}

__global__ __launch_bounds__(512) void k_final(
    const int2* __restrict__ ebuf, const int* __restrict__ base_,
    int* __restrict__ rs, int* __restrict__ srcs, int ndst, int etot, int nb)
{
    __shared__ int h[256];
    __shared__ int sc[256];
    int b = blockIdx.x, t = threadIdx.x;
    int base = base_[b];
    int cnt  = base_[b+1] - base;
    int d0 = b << 8;
    if (t < 256) h[t] = 0;
    __syncthreads();
    for (int i = t; i < cnt; i += 512) atomicAdd(&h[ebuf[base+i].y - d0], 1);
    __syncthreads();
    int v = (t < 256) ? h[t] : 0;
    if (t < 256) sc[t] = v;
    __syncthreads();
    for (int o = 1; o < 256; o <<= 1) {
        int a = (t < 256 && t >= o) ? sc[t-o] : 0;
        __syncthreads();
        if (t < 256) sc[t] += a;
        __syncthreads();
    }
    if (t < 256) {
        int gpos = base + sc[t] - v;
        if (d0 + t < ndst) rs[d0+t] = gpos;
        h[t] = gpos;
    }
    if (b == nb-1 && t == 0) rs[ndst] = etot;
    __syncthreads();
    for (int i = t; i < cnt; i += 512) {
        int2 ed = ebuf[base+i];
        int pos = atomicAdd(&h[ed.y - d0], 1);
        srcs[pos] = ed.x;
    }
}

// ================= compute kernels =================
// All node kernels: 2 nodes per wave-iteration (n must be even), readlane
// broadcast matvecs with even/odd split accumulators (4 indep fma chains).

// rel, x1 = relu([feat, rel]@feW + feb); fused gnn_pre layer0 -> p, q
__global__ __launch_bounds__(256) void k_feat_pre0(
    const float* __restrict__ feat, const float* __restrict__ pts,
    const float* __restrict__ ctr, const int* __restrict__ lab,
    const float* __restrict__ Wfe, const float* __restrict__ bfe,
    const float* __restrict__ Wh, const float* __restrict__ bh,
    const float* __restrict__ Wf, const float* __restrict__ bf,
    float* __restrict__ rel, float* __restrict__ x1,
    float* __restrict__ p, float* __restrict__ q, int n)
{
    int lane = threadIdx.x & 63;
    int wid  = blockIdx.x * (blockDim.x >> 6) + (threadIdx.x >> 6);
    int nw   = gridDim.x * (blockDim.x >> 6);
    float fe0 = Wfe[0*64+lane], fe1 = Wfe[1*64+lane], fe2 = Wfe[2*64+lane], fe3 = Wfe[3*64+lane];
    float fe4 = Wfe[4*64+lane], fe5 = Wfe[5*64+lane], fe6 = Wfe[6*64+lane];
    float bfe_l = bfe[lane];
    float wcol[64];
#pragma unroll
    for (int j = 0; j < 64; ++j) wcol[j] = Wf[(3+j)*64 + lane];
    float w0 = Wf[0*64+lane], w1 = Wf[1*64+lane], w2 = Wf[2*64+lane];
    float bfl = bf[lane];
    float wh0 = Wh[lane*3+0], wh1 = Wh[lane*3+1], wh2 = Wh[lane*3+2];
    float bh0 = bh[0], bh1 = bh[1], bh2 = bh[2];
    for (int i0 = wid*2; i0 < n; i0 += nw*2) {
        int iA = __builtin_amdgcn_readfirstlane(i0);
        int iB = iA + 1;
        int lA = lab[iA], lB = lab[iB];
        float pA0 = pts[iA*3+0], pA1 = pts[iA*3+1], pA2 = pts[iA*3+2];
        float pB0 = pts[iB*3+0], pB1 = pts[iB*3+1], pB2 = pts[iB*3+2];
        float rA0 = pA0 - ctr[lA*3+0], rA1 = pA1 - ctr[lA*3+1], rA2 = pA2 - ctr[lA*3+2];
        float rB0 = pB0 - ctr[lB*3+0], rB1 = pB1 - ctr[lB*3+1], rB2 = pB2 - ctr[lB*3+2];
        if (lane == 0)      { rel[iA*3+0]=rA0; rel[iA*3+1]=rA1; rel[iA*3+2]=rA2; }
        else if (lane == 1) { rel[iB*3+0]=rB0; rel[iB*3+1]=rB1; rel[iB*3+2]=rB2; }
        float aA = bfe_l, aB = bfe_l;
        aA = fmaf(feat[iA*4+0], fe0, aA); aB = fmaf(feat[iB*4+0], fe0, aB);
        aA = fmaf(feat[iA*4+1], fe1, aA); aB = fmaf(feat[iB*4+1], fe1, aB);
        aA = fmaf(feat[iA*4+2], fe2, aA); aB = fmaf(feat[iB*4+2], fe2, aB);
        aA = fmaf(feat[iA*4+3], fe3, aA); aB = fmaf(feat[iB*4+3], fe3, aB);
        aA = fmaf(rA0, fe4, aA); aB = fmaf(rB0, fe4, aB);
        aA = fmaf(rA1, fe5, aA); aB = fmaf(rB1, fe5, aB);
        aA = fmaf(rA2, fe6, aA); aB = fmaf(rB2, fe6, aB);
        float xvA = fmaxf(aA, 0.f), xvB = fmaxf(aB, 0.f);
        x1[(size_t)iA*64+lane] = xvA;
        x1[(size_t)iB*64+lane] = xvB;
        float d0A = xvA*wh0, d1A = xvA*wh1, d2A = xvA*wh2;
        float d0B = xvB*wh0, d1B = xvB*wh1, d2B = xvB*wh2;
#pragma unroll
        for (int o = 32; o; o >>= 1) {
            d0A += __shfl_xor(d0A,o); d1A += __shfl_xor(d1A,o); d2A += __shfl_xor(d2A,o);
            d0B += __shfl_xor(d0B,o); d1B += __shfl_xor(d1B,o); d2B += __shfl_xor(d2B,o);
        }
        d0A = tanhf(d0A+bh0); d1A = tanhf(d1A+bh1); d2A = tanhf(d2A+bh2);
        d0B = tanhf(d0B+bh0); d1B = tanhf(d1B+bh1); d2B = tanhf(d2B+bh2);
        float s0A=0.f, s1A=0.f, s0B=0.f, s1B=0.f;
#pragma unroll
        for (int j = 0; j < 64; j += 2) {
            s0A = fmaf(bcast(xvA,j),   wcol[j],   s0A);
            s1A = fmaf(bcast(xvA,j+1), wcol[j+1], s1A);
            s0B = fmaf(bcast(xvB,j),   wcol[j],   s0B);
            s1B = fmaf(bcast(xvB,j+1), wcol[j+1], s1B);
        }
        p[(size_t)iA*64+lane] = s0A+s1A + pA0*w0 + pA1*w1 + pA2*w2;
        p[(size_t)iB*64+lane] = s0B+s1B + pB0*w0 + pB1*w1 + pB2*w2;
        q[(size_t)iA*64+lane] = (d0A-pA0)*w0 + (d1A-pA1)*w1 + (d2A-pA2)*w2 + bfl;
        q[(size_t)iB*64+lane] = (d0B-pB0)*w0 + (d1B-pB1)*w1 + (d2B-pB2)*w2 + bfl;
    }
}

// CSR gather-max fused with relu(max+q) in place into q; 2 dests/wave, 4 streams.
__global__ __launch_bounds__(256) void k_seg_max_gnn(
    const int* __restrict__ rs, const int* __restrict__ srcs,
    const float* __restrict__ p, float* __restrict__ q, int n)
{
    int lane = threadIdx.x & 63;
    int wid  = blockIdx.x * (blockDim.x >> 6) + (threadIdx.x >> 6);
    int nw   = gridDim.x * (blockDim.x >> 6);
    for (int d0 = wid*2; d0 < n; d0 += nw*2) {
        int dA = __builtin_amdgcn_readfirstlane(d0);
        int begA = rs[dA], endA = rs[dA+1], endB = rs[dA+2];
        int ca = begA, cb = endA;
        float aA0=-1e30f, aA1=-1e30f, aB0=-1e30f, aB1=-1e30f;
        while (ca+2 <= endA && cb+2 <= endB) {
            int s0=srcs[ca], s1=srcs[ca+1], s2=srcs[cb], s3=srcs[cb+1];
            aA0 = fmaxf(aA0, p[(size_t)s0*64+lane]);
            aA1 = fmaxf(aA1, p[(size_t)s1*64+lane]);
            aB0 = fmaxf(aB0, p[(size_t)s2*64+lane]);
            aB1 = fmaxf(aB1, p[(size_t)s3*64+lane]);
            ca += 2; cb += 2;
        }
        while (ca+2 <= endA) {
            int s0=srcs[ca], s1=srcs[ca+1];
            aA0 = fmaxf(aA0, p[(size_t)s0*64+lane]);
            aA1 = fmaxf(aA1, p[(size_t)s1*64+lane]);
            ca += 2;
        }
        while (cb+2 <= endB) {
            int s2=srcs[cb], s3=srcs[cb+1];
            aB0 = fmaxf(aB0, p[(size_t)s2*64+lane]);
            aB1 = fmaxf(aB1, p[(size_t)s3*64+lane]);
            cb += 2;
        }
        if (ca < endA) aA0 = fmaxf(aA0, p[(size_t)srcs[ca]*64+lane]);
        if (cb < endB) aB0 = fmaxf(aB0, p[(size_t)srcs[cb]*64+lane]);
        float accA = fmaxf(aA0, aA1), accB = fmaxf(aB0, aB1);
        size_t oA = (size_t)dA*64 + lane, oB = oA + 64;
        q[oA] = fmaxf(accA + q[oA], 0.f);
        q[oB] = fmaxf(accB + q[oB], 0.f);
    }
}

// x2 = relu(agg@Wg+bg)+x1; h = relu([x2,rel]@Wm+bm)
__global__ __launch_bounds__(256) void k_post_m2l(
    const float* __restrict__ agg, const float* __restrict__ Wg,
    const float* __restrict__ bg, const float* __restrict__ x1,
    const float* __restrict__ rel,
    const float* __restrict__ Wm, const float* __restrict__ bm,
    float* __restrict__ x2, float* __restrict__ h, int n)
{
    int lane = threadIdx.x & 63;
    int wid  = blockIdx.x * (blockDim.x >> 6) + (threadIdx.x >> 6);
    int nw   = gridDim.x * (blockDim.x >> 6);
    float wg[64], wm[64];
#pragma unroll
    for (int j = 0; j < 64; ++j) { wg[j] = Wg[j*64 + lane]; wm[j] = Wm[j*64 + lane]; }
    float wm64 = Wm[64*64+lane], wm65 = Wm[65*64+lane], wm66 = Wm[66*64+lane];
    float bgl = bg[lane], bml = bm[lane];
    for (int i0 = wid*2; i0 < n; i0 += nw*2) {
        int iA = __builtin_amdgcn_readfirstlane(i0);
        int iB = iA + 1;
        size_t oA = (size_t)iA*64 + lane, oB = oA + 64;
        float avA = agg[oA], avB = agg[oB];
        float s0A=0.f, s1A=0.f, s0B=0.f, s1B=0.f;
#pragma unroll
        for (int j = 0; j < 64; j += 2) {
            s0A = fmaf(bcast(avA,j),   wg[j],   s0A);
            s1A = fmaf(bcast(avA,j+1), wg[j+1], s1A);
            s0B = fmaf(bcast(avB,j),   wg[j],   s0B);
            s1B = fmaf(bcast(avB,j+1), wg[j+1], s1B);
        }
        float x2A = fmaxf(s0A+s1A + bgl, 0.f) + x1[oA];
        float x2B = fmaxf(s0B+s1B + bgl, 0.f) + x1[oB];
        x2[oA] = x2A; x2[oB] = x2B;
        float t0A=0.f, t1A=0.f, t0B=0.f, t1B=0.f;
#pragma unroll
        for (int j = 0; j < 64; j += 2) {
            t0A = fmaf(bcast(x2A,j),   wm[j],   t0A);
            t1A = fmaf(bcast(x2A,j+1), wm[j+1], t1A);
            t0B = fmaf(bcast(x2B,j),   wm[j],   t0B);
            t1B = fmaf(bcast(x2B,j+1), wm[j+1], t1B);
        }
        float hA = t0A+t1A + bml + rel[iA*3+0]*wm64 + rel[iA*3+1]*wm65 + rel[iA*3+2]*wm66;
        float hB = t0B+t1B + bml + rel[iB*3+0]*wm64 + rel[iB*3+1]*wm65 + rel[iB*3+2]*wm66;
        h[oA] = fmaxf(hA, 0.f);
        h[oB] = fmaxf(hB, 0.f);
    }
}

// c = segmax(h by labels); fused gnn_pre layer1 -> pa, qa   (M nodes, 2/wave)
__global__ __launch_bounds__(256) void k_seglab_pre1(
    const int* __restrict__ rsL, const int* __restrict__ srcsL,
    const float* __restrict__ h, const float* __restrict__ pos,
    const float* __restrict__ Wh, const float* __restrict__ bh,
    const float* __restrict__ Wf, const float* __restrict__ bf,
    float* __restrict__ c, float* __restrict__ pa, float* __restrict__ qa, int m)
{
    int lane = threadIdx.x & 63;
    int wid  = blockIdx.x * (blockDim.x >> 6) + (threadIdx.x >> 6);
    int nw   = gridDim.x * (blockDim.x >> 6);
    float wcol[64];
#pragma unroll
    for (int j = 0; j < 64; ++j) wcol[j] = Wf[(3+j)*64 + lane];
    float w0 = Wf[0*64+lane], w1 = Wf[1*64+lane], w2 = Wf[2*64+lane];
    float bfl = bf[lane];
    float wh0 = Wh[lane*3+0], wh1 = Wh[lane*3+1], wh2 = Wh[lane*3+2];
    float bh0 = bh[0], bh1 = bh[1], bh2 = bh[2];
    for (int d0 = wid*2; d0 < m; d0 += nw*2) {
        int dA = __builtin_amdgcn_readfirstlane(d0);
        int dB = dA + 1;
        int begA = rsL[dA], endA = rsL[dA+1], endB = rsL[dA+2];
        int ca = begA, cb = endA;
        float aA0=-1e30f, aA1=-1e30f, aB0=-1e30f, aB1=-1e30f;
        while (ca+2 <= endA && cb+2 <= endB) {
            int s0=srcsL[ca], s1=srcsL[ca+1], s2=srcsL[cb], s3=srcsL[cb+1];
            aA0 = fmaxf(aA0, h[(size_t)s0*64+lane]);
            aA1 = fmaxf(aA1, h[(size_t)s1*64+lane]);
            aB0 = fmaxf(aB0, h[(size_t)s2*64+lane]);
            aB1 = fmaxf(aB1, h[(size_t)s3*64+lane]);
            ca += 2; cb += 2;
        }
        while (ca+2 <= endA) {
            int s0=srcsL[ca], s1=srcsL[ca+1];
            aA0 = fmaxf(aA0, h[(size_t)s0*64+lane]);
            aA1 = fmaxf(aA1, h[(size_t)s1*64+lane]);
            ca += 2;
        }
        while (cb+2 <= endB) {
            int s2=srcsL[cb], s3=srcsL[cb+1];
            aB0 = fmaxf(aB0, h[(size_t)s2*64+lane]);
            aB1 = fmaxf(aB1, h[(size_t)s3*64+lane]);
            cb += 2;
        }
        if (ca < endA) aA0 = fmaxf(aA0, h[(size_t)srcsL[ca]*64+lane]);
        if (cb < endB) aB0 = fmaxf(aB0, h[(size_t)srcsL[cb]*64+lane]);
        float cvA = fmaxf(fmaxf(aA0,aA1), 0.f);
        float cvB = fmaxf(fmaxf(aB0,aB1), 0.f);
        c[(size_t)dA*64+lane] = cvA;
        c[(size_t)dB*64+lane] = cvB;
        float d0A = cvA*wh0, d1A = cvA*wh1, d2A = cvA*wh2;
        float d0B = cvB*wh0, d1B = cvB*wh1, d2B = cvB*wh2;
#pragma unroll
        for (int o = 32; o; o >>= 1) {
            d0A += __shfl_xor(d0A,o); d1A += __shfl_xor(d1A,o); d2A += __shfl_xor(d2A,o);
            d0B += __shfl_xor(d0B,o); d1B += __shfl_xor(d1B,o); d2B += __shfl_xor(d2B,o);
        }
        d0A = tanhf(d0A+bh0); d1A = tanhf(d1A+bh1); d2A = tanhf(d2A+bh2);
        d0B = tanhf(d0B+bh0); d1B = tanhf(d1B+bh1); d2B = tanhf(d2B+bh2);
        float pA0 = pos[dA*3+0], pA1 = pos[dA*3+1], pA2 = pos[dA*3+2];
        float pB0 = pos[dB*3+0], pB1 = pos[dB*3+1], pB2 = pos[dB*3+2];
        float s0A=0.f, s1A=0.f, s0B=0.f, s1B=0.f;
#pragma unroll
        for (int j = 0; j < 64; j += 2) {
            s0A = fmaf(bcast(cvA,j),   wcol[j],   s0A);
            s1A = fmaf(bcast(cvA,j+1), wcol[j+1], s1A);
            s0B = fmaf(bcast(cvB,j),   wcol[j],   s0B);
            s1B = fmaf(bcast(cvB,j+1), wcol[j+1], s1B);
        }
        pa[(size_t)dA*64+lane] = s0A+s1A + pA0*w0 + pA1*w1 + pA2*w2;
        pa[(size_t)dB*64+lane] = s0B+s1B + pB0*w0 + pB1*w1 + pB2*w2;
        qa[(size_t)dA*64+lane] = (d0A-pA0)*w0 + (d1A-pA1)*w1 + (d2A-pA2)*w2 + bfl;
        qa[(size_t)dB*64+lane] = (d0B-pB0)*w0 + (d1B-pB1)*w1 + (d2B-pB2)*w2 + bfl;
    }
}

// out = relu(agg@Wg + bg) + xres
__global__ __launch_bounds__(256) void k_gnn_post(
    const float* __restrict__ agg, const float* __restrict__ Wg,
    const float* __restrict__ bg, const float* __restrict__ xres,
    float* __restrict__ out, int n)
{
    int lane = threadIdx.x & 63;
    int wid  = blockIdx.x * (blockDim.x >> 6) + (threadIdx.x >> 6);
    int nw   = gridDim.x * (blockDim.x >> 6);
    float wcol[64];
#pragma unroll
    for (int j = 0; j < 64; ++j) wcol[j] = Wg[j*64 + lane];
    float bgl = bg[lane];
    for (int i0 = wid*2; i0 < n; i0 += nw*2) {
        int iA = __builtin_amdgcn_readfirstlane(i0);
        size_t oA = (size_t)iA*64 + lane, oB = oA + 64;
        float avA = agg[oA], avB = agg[oB];
        float s0A=0.f, s1A=0.f, s0B=0.f, s1B=0.f;
#pragma unroll
        for (int j = 0; j < 64; j += 2) {
            s0A = fmaf(bcast(avA,j),   wcol[j],   s0A);
            s1A = fmaf(bcast(avA,j+1), wcol[j+1], s1A);
            s0B = fmaf(bcast(avB,j),   wcol[j],   s0B);
            s1B = fmaf(bcast(avB,j+1), wcol[j+1], s1B);
        }
        out[oA] = fmaxf(s0A+s1A + bgl, 0.f) + xres[oA];
        out[oB] = fmaxf(s0B+s1B + bgl, 0.f) + xres[oB];
    }
}

// x5 = relu([c4[lab], rel]@Wm+bm); fused gnn_pre layer2 -> p, q
__global__ __launch_bounds__(256) void k_l2m_pre2(
    const float* __restrict__ c4, const int* __restrict__ lab,
    const float* __restrict__ rel, const float* __restrict__ pts,
    const float* __restrict__ Wm, const float* __restrict__ bm,
    const float* __restrict__ Wh, const float* __restrict__ bh,
    const float* __restrict__ Wf, const float* __restrict__ bf,
    float* __restrict__ x5, float* __restrict__ p, float* __restrict__ q, int n)
{
    int lane = threadIdx.x & 63;
    int wid  = blockIdx.x * (blockDim.x >> 6) + (threadIdx.x >> 6);
    int nw   = gridDim.x * (blockDim.x >> 6);
    float wm[64], wf[64];
#pragma unroll
    for (int j = 0; j < 64; ++j) { wm[j] = Wm[j*64 + lane]; wf[j] = Wf[(3+j)*64 + lane]; }
    float wm64 = Wm[64*64+lane], wm65 = Wm[65*64+lane], wm66 = Wm[66*64+lane];
    float w0 = Wf[0*64+lane], w1 = Wf[1*64+lane], w2 = Wf[2*64+lane];
    float bml = bm[lane], bfl = bf[lane];
    float wh0 = Wh[lane*3+0], wh1 = Wh[lane*3+1], wh2 = Wh[lane*3+2];
    float bh0 = bh[0], bh1 = bh[1], bh2 = bh[2];
    for (int i0 = wid*2; i0 < n; i0 += nw*2) {
        int iA = __builtin_amdgcn_readfirstlane(i0);
        int iB = iA + 1;
        int lA = lab[iA], lB = lab[iB];
        float cvA = c4[(size_t)lA*64 + lane];
        float cvB = c4[(size_t)lB*64 + lane];
        float s0A=0.f, s1A=0.f, s0B=0.f, s1B=0.f;
#pragma unroll
        for (int j = 0; j < 64; j += 2) {
            s0A = fmaf(bcast(cvA,j),   wm[j],   s0A);
            s1A = fmaf(bcast(cvA,j+1), wm[j+1], s1A);
            s0B = fmaf(bcast(cvB,j),   wm[j],   s0B);
            s1B = fmaf(bcast(cvB,j+1), wm[j+1], s1B);
        }
        float hA = s0A+s1A + bml + rel[iA*3+0]*wm64 + rel[iA*3+1]*wm65 + rel[iA*3+2]*wm66;
        float hB = s0B+s1B + bml + rel[iB*3+0]*wm64 + rel[iB*3+1]*wm65 + rel[iB*3+2]*wm66;
        float xvA = fmaxf(hA, 0.f), xvB = fmaxf(hB, 0.f);
        size_t oA = (size_t)iA*64 + lane, oB = oA + 64;
        x5[oA] = xvA; x5[oB] = xvB;
        float d0A = xvA*wh0, d1A = xvA*wh1, d2A = xvA*wh2;
        float d0B = xvB*wh0, d1B = xvB*wh1, d2B = xvB*wh2;
#pragma unroll
        for (int o = 32; o; o >>= 1) {
            d0A += __shfl_xor(d0A,o); d1A += __shfl_xor(d1A,o); d2A += __shfl_xor(d2A,o);
            d0B += __shfl_xor(d0B,o); d1B += __shfl_xor(d1B,o); d2B += __shfl_xor(d2B,o);
        }
        d0A = tanhf(d0A+bh0); d1A = tanhf(d1A+bh1); d2A = tanhf(d2A+bh2);
        d0B = tanhf(d0B+bh0); d1B = tanhf(d1B+bh1); d2B = tanhf(d2B+bh2);
        float pA0 = pts[iA*3+0], pA1 = pts[iA*3+1], pA2 = pts[iA*3+2];
        float pB0 = pts[iB*3+0], pB1 = pts[iB*3+1], pB2 = pts[iB*3+2];
        float t0A=0.f, t1A=0.f, t0B=0.f, t1B=0.f;
#pragma unroll
        for (int j = 0; j < 64; j += 2) {
            t0A = fmaf(bcast(xvA,j),   wf[j],   t0A);
            t1A = fmaf(bcast(xvA,j+1), wf[j+1], t1A);
            t0B = fmaf(bcast(xvB,j),   wf[j],   t0B);
            t1B = fmaf(bcast(xvB,j+1), wf[j+1], t1B);
        }
        p[oA] = t0A+t1A + pA0*w0 + pA1*w1 + pA2*w2;
        p[oB] = t0B+t1B + pB0*w0 + pB1*w1 + pB2*w2;
        q[oA] = (d0A-pA0)*w0 + (d1A-pA1)*w1 + (d2A-pA2)*w2 + bfl;
        q[oB] = (d0B-pB0)*w0 + (d1B-pB1)*w1 + (d2B-pB2)*w2 + bfl;
    }
}

// x6 = relu(agg@Wg+bg)+x5; fin = x6+x2; t = relu(fin@W1+b1); out = t@W2+b2
__global__ __launch_bounds__(256) void k_gnn_post_final(
    const float* __restrict__ agg, const float* __restrict__ Wg,
    const float* __restrict__ bg,
    const float* __restrict__ x5, const float* __restrict__ x2,
    const float* __restrict__ W1, const float* __restrict__ b1,
    const float* __restrict__ W2, const float* __restrict__ b2,
    float* __restrict__ out, int n)
{
    int lane = threadIdx.x & 63;
    int wid  = blockIdx.x * (blockDim.x >> 6) + (threadIdx.x >> 6);
    int nw   = gridDim.x * (blockDim.x >> 6);
    float wg[64], w1c[64];
#pragma unroll
    for (int j = 0; j < 64; ++j) { wg[j] = Wg[j*64 + lane]; w1c[j] = W1[j*64 + lane]; }
    float w2c0 = W2[lane*4+0], w2c1 = W2[lane*4+1], w2c2 = W2[lane*4+2], w2c3 = W2[lane*4+3];
    float bgl = bg[lane], b1l = b1[lane];
    float b20 = b2[0], b21 = b2[1], b22 = b2[2], b23 = b2[3];
    for (int i0 = wid*2; i0 < n; i0 += nw*2) {
        int iA = __builtin_amdgcn_readfirstlane(i0);
        int iB = iA + 1;
        size_t oA = (size_t)iA*64 + lane, oB = oA + 64;
        float avA = agg[oA], avB = agg[oB];
        float s0A=0.f, s1A=0.f, s0B=0.f, s1B=0.f;
#pragma unroll
        for (int j = 0; j < 64; j += 2) {
            s0A = fmaf(bcast(avA,j),   wg[j],   s0A);
            s1A = fmaf(bcast(avA,j+1), wg[j+1], s1A);
            s0B = fmaf(bcast(avB,j),   wg[j],   s0B);
            s1B = fmaf(bcast(avB,j+1), wg[j+1], s1B);
        }
        float finA = fmaxf(s0A+s1A + bgl, 0.f) + x5[oA] + x2[oA];
        float finB = fmaxf(s0B+s1B + bgl, 0.f) + x5[oB] + x2[oB];
        float t0A=0.f, t1A=0.f, t0B=0.f, t1B=0.f;
#pragma unroll
        for (int j = 0; j < 64; j += 2) {
            t0A = fmaf(bcast(finA,j),   w1c[j],   t0A);
            t1A = fmaf(bcast(finA,j+1), w1c[j+1], t1A);
            t0B = fmaf(bcast(finB,j),   w1c[j],   t0B);
            t1B = fmaf(bcast(finB,j+1), w1c[j+1], t1B);
        }
        float tA = fmaxf(t0A+t1A + b1l, 0.f);
        float tB = fmaxf(t0B+t1B + b1l, 0.f);
        float o0A = wredsum(tA * w2c0), o1A = wredsum(tA * w2c1);
        float o2A = wredsum(tA * w2c2), o3A = wredsum(tA * w2c3);
        float o0B = wredsum(tB * w2c0), o1B = wredsum(tB * w2c1);
        float o2B = wredsum(tB * w2c2), o3B = wredsum(tB * w2c3);
        if (lane == 0) {
            *(float4*)(out + (size_t)iA*4) = make_float4(o0A+b20, o1A+b21, o2A+b22, o3A+b23);
            *(float4*)(out + (size_t)iB*4) = make_float4(o0B+b20, o1B+b21, o2B+b22, o3B+b23);
        }
    }
}

// ---------------- launch ----------------

extern "C" void kernel_launch(void* const* d_in, const int* in_sizes, int n_in,
                              void* d_out, int out_size, void* d_ws, size_t ws_size,
                              hipStream_t stream)
{
    const int N = 100000, M = 10000, E0 = 1600000, E1 = 320000;
    const int NB0 = (N + 255) / 256;   // 391
    const int NB1 = (M + 255) / 256;   // 40
    const int NBL = (M + 255) / 256;   // 40

    const float* feat = (const float*)d_in[0];
    const float* pts  = (const float*)d_in[1];
    const float* ctr  = (const float*)d_in[2];
    const int*   lab  = (const int*)d_in[3];
    const int2*  e0   = (const int2*)d_in[4];
    const int2*  e1   = (const int2*)d_in[5];
    const float* feW  = (const float*)d_in[6];
    const float* feb  = (const float*)d_in[7];
    const float* Wh   = (const float*)d_in[8];
    const float* bh   = (const float*)d_in[9];
    const float* Wf   = (const float*)d_in[10];
    const float* bf   = (const float*)d_in[11];
    const float* Wg   = (const float*)d_in[12];
    const float* bg   = (const float*)d_in[13];
    const float* m2lW = (const float*)d_in[14];
    const float* m2lb = (const float*)d_in[15];
    const float* l2mW = (const float*)d_in[16];
    const float* l2mb = (const float*)d_in[17];
    const float* cW1  = (const float*)d_in[18];
    const float* cb1  = (const float*)d_in[19];
    const float* cW2  = (const float*)d_in[20];
    const float* cb2  = (const float*)d_in[21];
    float* out = (float*)d_out;

    char* ws = (char*)d_ws;
    size_t off = 0;
    auto alloc = [&](size_t bytes) -> char* {
        char* r = ws + off; off += (bytes + 255) & ~(size_t)255; return r;
    };
    float* rel   = (float*)alloc((size_t)N*3*4);
    float* x1    = (float*)alloc((size_t)N*64*4);   // x1, later x5
    float* x2    = (float*)alloc((size_t)N*64*4);   // also hosts ebufs pre-compute
    float* p     = (float*)alloc((size_t)N*64*4);   // p0 / h / p2
    float* q     = (float*)alloc((size_t)N*64*4);   // q0/agg, [p1|q1], q2
    float* c     = (float*)alloc((size_t)M*64*4);
    float* c4    = (float*)alloc((size_t)M*64*4);
    int* rs0     = (int*)alloc((size_t)(N+2)*4);
    int* srcs0   = (int*)alloc((size_t)E0*4);
    int* rs1     = (int*)alloc((size_t)(M+2)*4);
    int* srcs1   = (int*)alloc((size_t)E1*4);
    int* rsL     = (int*)alloc((size_t)(M+2)*4);
    int* srcsL   = (int*)alloc((size_t)N*4);
    int* cnt0    = (int*)alloc((size_t)NB0*4);
    int* cnt1    = (int*)alloc((size_t)NB1*4);
    int* cntL    = (int*)alloc((size_t)NBL*4);
    int* base0   = (int*)alloc((size_t)(NB0+1)*4);
    int* base1   = (int*)alloc((size_t)(NB1+1)*4);
    int* baseL   = (int*)alloc((size_t)(NBL+1)*4);
    int* cur0    = (int*)alloc((size_t)NB0*4);
    int* cur1    = (int*)alloc((size_t)NB1*4);
    int* curL    = (int*)alloc((size_t)NBL*4);
    (void)ws_size; (void)in_sizes; (void)n_in; (void)out_size;

    int2* ebuf0 = (int2*)x2;
    int2* ebuf1 = ebuf0 + E0;
    int2* ebufL = ebuf1 + E1;

    dim3 blk(256);
    const int gridN = 2048, gridM = 640;

    // ---- CSR builds ----
    hipMemsetAsync(cnt0, 0, (size_t)NB0*4, stream);
    hipMemsetAsync(cnt1, 0, (size_t)NB1*4, stream);
    hipMemsetAsync(cntL, 0, (size_t)NBL*4, stream);
    k_bhist_e<<<1024, blk, 0, stream>>>(e0, cnt0, E0, NB0);
    k_bhist_e<<<512,  blk, 0, stream>>>(e1, cnt1, E1, NB1);
    k_bhist_l<<<512,  blk, 0, stream>>>(lab, cntL, N, NBL);
    k_bscan3<<<3, 512, 0, stream>>>(cnt0, base0, cur0, NB0, E0,
                                    cnt1, base1, cur1, NB1, E1,
                                    cntL, baseL, curL, NBL, N);
    k_bucket_e<<<(E0 + BKT*EPT - 1)/(BKT*EPT), BKT, 0, stream>>>(e0, cur0, ebuf0, E0, NB0);
    k_bucket_e<<<(E1 + BKT*EPT - 1)/(BKT*EPT), BKT, 0, stream>>>(e1, cur1, ebuf1, E1, NB1);
    k_bucket_l<<<(N  + BKT*EPT - 1)/(BKT*EPT), BKT, 0, stream>>>(lab, curL, ebufL, N, NBL);
    k_final<<<NB0, 512, 0, stream>>>(ebuf0, base0, rs0, srcs0, N, E0, NB0);
    k_final<<<NB1, 512, 0, stream>>>(ebuf1, base1, rs1, srcs1, M, E1, NB1);
    k_final<<<NBL, 512, 0, stream>>>(ebufL, baseL, rsL, srcsL, M, N, NBL);

    // ---- layer 0 ----
    k_feat_pre0<<<gridN, blk, 0, stream>>>(feat, pts, ctr, lab, feW, feb,
                                           Wh+0*64*3, bh+0*3, Wf+0*67*64, bf+0*64,
                                           rel, x1, p, q, N);
    k_seg_max_gnn<<<gridN, blk, 0, stream>>>(rs0, srcs0, p, q, N);
    k_post_m2l<<<gridN, blk, 0, stream>>>(q, Wg+0*64*64, bg+0*64, x1, rel,
                                          m2lW, m2lb, x2, p, N);

    // ---- layer 1 (clusters) ----
    float* p1 = q;
    float* q1 = q + (size_t)M*64;
    k_seglab_pre1<<<gridM, blk, 0, stream>>>(rsL, srcsL, p, ctr,
                                             Wh+1*64*3, bh+1*3, Wf+1*67*64, bf+1*64,
                                             c, p1, q1, M);
    k_seg_max_gnn<<<gridM, blk, 0, stream>>>(rs1, srcs1, p1, q1, M);
    k_gnn_post<<<gridM, blk, 0, stream>>>(q1, Wg+1*64*64, bg+1*64, c, c4, M);

    // ---- l2m + layer 2 + classifier ----
    k_l2m_pre2<<<gridN, blk, 0, stream>>>(c4, lab, rel, pts, l2mW, l2mb,
                                          Wh+2*64*3, bh+2*3, Wf+2*67*64, bf+2*64,
                                          x1, p, q, N);
    k_seg_max_gnn<<<gridN, blk, 0, stream>>>(rs0, srcs0, p, q, N);
    k_gnn_post_final<<<gridN, blk, 0, stream>>>(q, Wg+2*64*64, bg+2*64, x1, x2,
                                                cW1, cb1, cW2, cb2, out, N);
}